// Round 3
// baseline (2919.763 us; speedup 1.0000x reference)
//
#include <hip/hip_runtime.h>
#include <hip/hip_bf16.h>
#include <math.h>

#define NTOK 8192
#define HD 1024
#define ID 4096
#define NE 8
#define MAXTILES 40   // 256-row token tiles: <= 32 full + 8 partial
#define SORTT 512
#define TPT (NTOK / SORTT)  // 16 tokens per sort thread

typedef __attribute__((ext_vector_type(8))) short short8;
typedef __attribute__((ext_vector_type(8))) unsigned short ushort8;
typedef __attribute__((ext_vector_type(4))) float floatx4;

__device__ __forceinline__ unsigned short f2bf(float f) {
  unsigned int u = __float_as_uint(f);
  return (unsigned short)((u + 0x7fffu + ((u >> 16) & 1u)) >> 16);
}

__device__ __forceinline__ void async_ld16(const void* g, void* l) {
  __builtin_amdgcn_global_load_lds(
      (const __attribute__((address_space(1))) unsigned int*)g,
      (__attribute__((address_space(3))) unsigned int*)l,
      16, 0, 0);
}

// ---------------- small kernels ----------------

__global__ void transpose_cast_kernel(const float* __restrict__ src,
                                      unsigned short* __restrict__ dst, int R, int C) {
  size_t bo = (size_t)blockIdx.z * R * C;
  src += bo; dst += bo;
  __shared__ float t[64][65];
  int c0 = blockIdx.x * 64, r0 = blockIdx.y * 64;
  int tid = threadIdx.x;
  int rr = tid >> 4, c4 = (tid & 15) * 4;
#pragma unroll
  for (int q = 0; q < 4; q++) {
    int r = rr + q * 16;
    float4 v = *(const float4*)(src + (size_t)(r0 + r) * C + c0 + c4);
    t[r][c4] = v.x; t[r][c4 + 1] = v.y; t[r][c4 + 2] = v.z; t[r][c4 + 3] = v.w;
  }
  __syncthreads();
  int r8 = (tid & 7) * 8;
#pragma unroll
  for (int q = 0; q < 2; q++) {
    int cc = (tid >> 3) + q * 32;
    ushort8 o;
#pragma unroll
    for (int i = 0; i < 8; i++) o[i] = f2bf(t[r8 + i][cc]);
    *(ushort8*)(dst + (size_t)(c0 + cc) * R + r0 + r8) = o;
  }
}

__global__ void router_kernel(const float* __restrict__ x, const float* __restrict__ wr,
                              int* __restrict__ eidx, unsigned short* __restrict__ xb) {
  int wave = threadIdx.x >> 6, lane = threadIdx.x & 63;
  int n = blockIdx.x * 4 + wave;
  const float* xr = x + (size_t)n * HD;
  unsigned short* xbr = xb + (size_t)n * HD;
  double acc[NE];
#pragma unroll
  for (int e = 0; e < NE; e++) acc[e] = 0.0;
#pragma unroll
  for (int v = 0; v < 4; v++) {
    int h = (lane + v * 64) * 4;
    float4 xv = *(const float4*)(xr + h);
    ushort4 o;
    o.x = f2bf(xv.x); o.y = f2bf(xv.y); o.z = f2bf(xv.z); o.w = f2bf(xv.w);
    *(ushort4*)(xbr + h) = o;
#pragma unroll
    for (int e = 0; e < NE; e++) {
      float4 wv = *(const float4*)(wr + e * HD + h);
      acc[e] += (double)xv.x * wv.x + (double)xv.y * wv.y +
                (double)xv.z * wv.z + (double)xv.w * wv.w;
    }
  }
#pragma unroll
  for (int m = 32; m >= 1; m >>= 1) {
#pragma unroll
    for (int e = 0; e < NE; e++) acc[e] += __shfl_xor(acc[e], m, 64);
  }
  if (lane == 0) {
    int best = 0; double bv = acc[0];
#pragma unroll
    for (int e = 1; e < NE; e++) if (acc[e] > bv) { bv = acc[e]; best = e; }
    eidx[n] = best;
  }
}

// counting sort -> perm + 256-row tile table (scratch-free, proven R6)
__global__ __launch_bounds__(SORTT) void sort_kernel(
    const int* __restrict__ eidx, int* __restrict__ ntiles, int* __restrict__ tile_e,
    int* __restrict__ tile_base, int* __restrict__ tile_len, int* __restrict__ perm) {
  __shared__ int h[NE][SORTT];
  __shared__ int off_sh[NE];
  __shared__ int tot[NE];
  int t = threadIdx.x;
  int wave = t >> 6, lane = t & 63;
  const int base = t * TPT;

  int4 e0 = *(const int4*)(eidx + base);
  int4 e1 = *(const int4*)(eidx + base + 4);
  int4 e2 = *(const int4*)(eidx + base + 8);
  int4 e3 = *(const int4*)(eidx + base + 12);
  int ex[TPT] = {e0.x, e0.y, e0.z, e0.w, e1.x, e1.y, e1.z, e1.w,
                 e2.x, e2.y, e2.z, e2.w, e3.x, e3.y, e3.z, e3.w};
  int cnt0 = 0, cnt1 = 0, cnt2 = 0, cnt3 = 0, cnt4 = 0, cnt5 = 0, cnt6 = 0, cnt7 = 0;
#pragma unroll
  for (int i = 0; i < TPT; i++) {
    int e = ex[i];
    cnt0 += (e == 0); cnt1 += (e == 1); cnt2 += (e == 2); cnt3 += (e == 3);
    cnt4 += (e == 4); cnt5 += (e == 5); cnt6 += (e == 6); cnt7 += (e == 7);
  }
  h[0][t] = cnt0; h[1][t] = cnt1; h[2][t] = cnt2; h[3][t] = cnt3;
  h[4][t] = cnt4; h[5][t] = cnt5; h[6][t] = cnt6; h[7][t] = cnt7;
  __syncthreads();

  {
    int e = wave;
    int v[8], s = 0;
#pragma unroll
    for (int i = 0; i < 8; i++) { v[i] = h[e][lane * 8 + i]; s += v[i]; }
    int inc = s;
#pragma unroll
    for (int d = 1; d < 64; d <<= 1) {
      int o = __shfl_up(inc, d, 64);
      if (lane >= d) inc += o;
    }
    int exc = inc - s;
#pragma unroll
    for (int i = 0; i < 8; i++) { h[e][lane * 8 + i] = exc; exc += v[i]; }
    if (lane == 63) tot[e] = inc;
  }
  __syncthreads();

  if (t == 0) {
    int s = 0, tt = 0;
    for (int e = 0; e < NE; e++) {
      off_sh[e] = s;
      int c = tot[e];
      for (int b = 0; b < c; b += 256) {
        tile_e[tt] = e;
        tile_base[tt] = s + b;
        tile_len[tt] = (c - b < 256) ? (c - b) : 256;
        tt++;
      }
      s += c;
    }
    *ntiles = tt;
  }
  __syncthreads();

  int c0c = off_sh[0] + h[0][t], c1c = off_sh[1] + h[1][t];
  int c2c = off_sh[2] + h[2][t], c3c = off_sh[3] + h[3][t];
  int c4c = off_sh[4] + h[4][t], c5c = off_sh[5] + h[5][t];
  int c6c = off_sh[6] + h[6][t], c7c = off_sh[7] + h[7][t];
#pragma unroll
  for (int i = 0; i < TPT; i++) {
    int e = ex[i];
    int pos = c0c;
    pos = (e == 1) ? c1c : pos; pos = (e == 2) ? c2c : pos;
    pos = (e == 3) ? c3c : pos; pos = (e == 4) ? c4c : pos;
    pos = (e == 5) ? c5c : pos; pos = (e == 6) ? c6c : pos;
    pos = (e == 7) ? c7c : pos;
    perm[pos] = base + i;
    c0c += (e == 0); c1c += (e == 1); c2c += (e == 2); c3c += (e == 3);
    c4c += (e == 4); c5c += (e == 5); c6c += (e == 6); c7c += (e == 7);
  }
}

// y = x + bo (residual+bias pre-init; ffn2 atomically accumulates on top)
__global__ void init_y_kernel(const float* __restrict__ x, const float* __restrict__ bo,
                              float* __restrict__ y) {
  int row = blockIdx.x, t = threadIdx.x;
  float4 xv = *(const float4*)(x + (size_t)row * HD + t * 4);
  float4 bv = *(const float4*)(bo + t * 4);
  float4 o = {xv.x + bv.x, xv.y + bv.y, xv.z + bv.z, xv.w + bv.w};
  *(float4*)(y + (size_t)row * HD + t * 4) = o;
}

// ---------------- 256x256 GEMM core, BK=32, single-buffered ----------------
// R7: back to the PROVEN R4 loop regime (stage -> sync -> compute -> sync;
// cross-block wave overlap does the latency hiding — R4 sustained 5.5 TB/s
// aggregate reads vs 3.2 for the 1-block/CU lockstep R6).  Changes vs R4:
//  * 256x256 tile halves global bytes (A re-read x16, not x32; B x4 not x8).
//  * BK=32 -> LDS only 2x16KB=32KB/block -> 4 blocks/CU (thread-capped),
//    de-correlated barriers across blocks = high memory-level parallelism.
//  * 8 waves (2Mx4N), per-wave 128x64 output, acc[8][4] (layout proven R6).
// LDS tile [256 rows][32 cols] bf16; 16B chunk slot = c ^ ((row>>2)&3),
// staged linearly from pre-swizzled global source (c = (lane&3)^((lane>>4)&3));
// ds_read side max 2-way bank aliasing = free (m136).

template <int NKS>
__device__ __forceinline__ void gemm_core(
    const unsigned short* gA0, const unsigned short* gA1,
    const unsigned short* gB0, const unsigned short* gB1,
    unsigned short* lA, unsigned short* lB,
    int wave, int lane, floatx4 (&acc)[8][4]) {
  int c15 = lane & 15, q4 = lane >> 4;
  int wm = wave >> 2, wn = wave & 3;
  unsigned short* dA0 = lA + (wave * 16) * 32;
  unsigned short* dA1 = lA + (128 + wave * 16) * 32;
  unsigned short* dB0 = lB + (wave * 16) * 32;
  unsigned short* dB1 = lB + (128 + wave * 16) * 32;
  int aoff[8], boff[4];
#pragma unroll
  for (int i = 0; i < 8; i++) {
    int m = wm * 128 + i * 16 + c15;
    aoff[i] = m * 32 + (q4 ^ ((m >> 2) & 3)) * 8;
  }
#pragma unroll
  for (int j = 0; j < 4; j++) {
    int n = wn * 64 + j * 16 + c15;
    boff[j] = n * 32 + (q4 ^ ((n >> 2) & 3)) * 8;
  }
  for (int ko = 0; ko < NKS; ++ko) {
    async_ld16(gA0 + ko * 32, dA0);
    async_ld16(gA1 + ko * 32, dA1);
    async_ld16(gB0 + ko * 32, dB0);
    async_ld16(gB1 + ko * 32, dB1);
    __syncthreads();  // vmcnt(0) drain: tile resident
    short8 af[8], bf[4];
#pragma unroll
    for (int i = 0; i < 8; i++) af[i] = *(const short8*)(lA + aoff[i]);
#pragma unroll
    for (int j = 0; j < 4; j++) bf[j] = *(const short8*)(lB + boff[j]);
#pragma unroll
    for (int i = 0; i < 8; i++)
#pragma unroll
      for (int j = 0; j < 4; j++)
        acc[i][j] = __builtin_amdgcn_mfma_f32_16x16x32_bf16(af[i], bf[j], acc[i][j], 0, 0, 0);
    __syncthreads();  // WAR: done reading before next stage
  }
}

// ---------------- GEMM kernels ----------------

// grid: 1-D 16*MAXTILES.  XCD-swizzle decode: tile t = (slot>>4)*8 + xcd so a
// tile's 16 n-blocks (sharing its 0.5MB A-panel) are consecutive on ONE XCD.
__global__ __launch_bounds__(512, 8) void ffn1_kernel(
    const unsigned short* __restrict__ xb, const unsigned short* __restrict__ w1t,
    const float* __restrict__ b1, const int* __restrict__ perm,
    const int* __restrict__ ntiles, const int* __restrict__ tile_e,
    const int* __restrict__ tile_base, const int* __restrict__ tile_len,
    unsigned short* __restrict__ interb) {
  int w = blockIdx.x;
  int xcd = w & 7, slot = w >> 3;
  int nblk = slot & 15;
  int t = (slot >> 4) * 8 + xcd;
  if (t >= *ntiles) return;
  int e = tile_e[t], base = tile_base[t], len = tile_len[t];
  int nb = nblk * 256;

  __shared__ unsigned short lA[256 * 32];  // 16 KB
  __shared__ unsigned short lB[256 * 32];  // 16 KB

  int tid = threadIdx.x;
  int wave = tid >> 6, lane = tid & 63;
  int rA0 = wave * 16 + (lane >> 2), rA1 = 128 + rA0;
  int c = (lane & 3) ^ ((lane >> 4) & 3);  // pre-swizzled source chunk

  int tok0 = perm[base + (rA0 < len ? rA0 : len - 1)];
  int tok1 = perm[base + (rA1 < len ? rA1 : len - 1)];
  const unsigned short* gA0 = xb + (size_t)tok0 * HD + c * 8;
  const unsigned short* gA1 = xb + (size_t)tok1 * HD + c * 8;
  const unsigned short* gB0 = w1t + ((size_t)e * ID + nb + rA0) * HD + c * 8;
  const unsigned short* gB1 = w1t + ((size_t)e * ID + nb + rA1) * HD + c * 8;

  floatx4 acc[8][4];
#pragma unroll
  for (int i = 0; i < 8; i++)
#pragma unroll
    for (int j = 0; j < 4; j++) acc[i][j] = (floatx4){0.f, 0.f, 0.f, 0.f};

  gemm_core<HD / 32>(gA0, gA1, gB0, gB1, lA, lB, wave, lane, acc);

  int c15 = lane & 15, q4 = lane >> 4;
  int wm = wave >> 2, wn = wave & 3;
#pragma unroll
  for (int i = 0; i < 8; i++) {
#pragma unroll
    for (int r = 0; r < 4; r++) {
      int tr = wm * 128 + i * 16 + q4 * 4 + r;
      if (tr >= len) continue;
      int token = perm[base + tr];
#pragma unroll
      for (int j = 0; j < 4; j++) {
        int col = nb + wn * 64 + j * 16 + c15;
        float v = acc[i][j][r] + b1[e * ID + col];
        v = 0.5f * v * (1.0f + erff(v * 0.70710678118654752f));  // exact GELU
        interb[(size_t)token * ID + col] = f2bf(v);
      }
    }
  }
}

// split-K=4: grid 1-D 512 (4n x 32m x 4k), 2 blocks/CU.  XCD-swizzle: the 4
// n-blocks sharing an (m,k) A-slice are consecutive on one XCD.  Partials
// accumulated with HW fp32 atomics into y (= x + bo from init_y).
__global__ __launch_bounds__(512, 8) void ffn2_kernel(
    const unsigned short* __restrict__ interb, const unsigned short* __restrict__ wot,
    float* __restrict__ y) {
  int w = blockIdx.x;
  int xcd = w & 7, slot = w >> 3;
  int nblk = slot & 3;
  int id = (slot >> 2) * 8 + xcd;  // [0,128): (m,k) pair
  int tm = id >> 2, kc = id & 3;
  int nb = nblk * 256;
  int kbase = kc * (ID / 4);  // 1024-wide K chunk

  __shared__ unsigned short lA[256 * 32];
  __shared__ unsigned short lB[256 * 32];

  int tid = threadIdx.x;
  int wave = tid >> 6, lane = tid & 63;
  int rA0 = wave * 16 + (lane >> 2), rA1 = 128 + rA0;
  int c = (lane & 3) ^ ((lane >> 4) & 3);

  const unsigned short* gA0 = interb + (size_t)(tm * 256 + rA0) * ID + kbase + c * 8;
  const unsigned short* gA1 = interb + (size_t)(tm * 256 + rA1) * ID + kbase + c * 8;
  const unsigned short* gB0 = wot + (size_t)(nb + rA0) * ID + kbase + c * 8;
  const unsigned short* gB1 = wot + (size_t)(nb + rA1) * ID + kbase + c * 8;

  floatx4 acc[8][4];
#pragma unroll
  for (int i = 0; i < 8; i++)
#pragma unroll
    for (int j = 0; j < 4; j++) acc[i][j] = (floatx4){0.f, 0.f, 0.f, 0.f};

  gemm_core<(ID / 4) / 32>(gA0, gA1, gB0, gB1, lA, lB, wave, lane, acc);

  int c15 = lane & 15, q4 = lane >> 4;
  int wm = wave >> 2, wn = wave & 3;
#pragma unroll
  for (int i = 0; i < 8; i++) {
#pragma unroll
    for (int r = 0; r < 4; r++) {
      int row = tm * 256 + wm * 128 + i * 16 + q4 * 4 + r;
#pragma unroll
      for (int j = 0; j < 4; j++) {
        int col = nb + wn * 64 + j * 16 + c15;
        unsafeAtomicAdd(&y[(size_t)row * HD + col], acc[i][j][r]);
      }
    }
  }
}

__global__ void ln_kernel(float* __restrict__ y, const float* __restrict__ gamma,
                          const float* __restrict__ beta) {
  int row = blockIdx.x, t = threadIdx.x;
  int lane = t & 63, wave = t >> 6;
  float* yr = y + (size_t)row * HD;
  float4 v = *(const float4*)(yr + t * 4);
  float s = v.x + v.y + v.z + v.w;
  float ss = v.x * v.x + v.y * v.y + v.z * v.z + v.w * v.w;
#pragma unroll
  for (int m = 32; m >= 1; m >>= 1) {
    s += __shfl_xor(s, m, 64);
    ss += __shfl_xor(ss, m, 64);
  }
  __shared__ float sred[4], ssred[4];
  if (lane == 0) { sred[wave] = s; ssred[wave] = ss; }
  __syncthreads();
  s = sred[0] + sred[1] + sred[2] + sred[3];
  ss = ssred[0] + ssred[1] + ssred[2] + ssred[3];
  float mu = s * (1.0f / HD);
  float var = ss * (1.0f / HD) - mu * mu;
  float rs = rsqrtf(var + 1e-12f);
  float4 g = *(const float4*)(gamma + t * 4);
  float4 b = *(const float4*)(beta + t * 4);
  float4 o;
  o.x = (v.x - mu) * rs * g.x + b.x;
  o.y = (v.y - mu) * rs * g.y + b.y;
  o.z = (v.z - mu) * rs * g.z + b.z;
  o.w = (v.w - mu) * rs * g.w + b.w;
  *(float4*)(yr + t * 4) = o;
}

// ---------------- host launcher ----------------

extern "C" void kernel_launch(void* const* d_in, const int* in_sizes, int n_in,
                              void* d_out, int out_size, void* d_ws, size_t ws_size,
                              hipStream_t stream) {
  const float* x     = (const float*)d_in[0];
  const float* wr    = (const float*)d_in[1];
  const float* w1    = (const float*)d_in[2];
  const float* b1    = (const float*)d_in[3];
  const float* wo    = (const float*)d_in[4];
  const float* bo    = (const float*)d_in[5];
  const float* gamma = (const float*)d_in[6];
  const float* beta  = (const float*)d_in[7];
  float* out = (float*)d_out;

  char* p = (char*)d_ws;
  unsigned short* w1t = (unsigned short*)p; p += (size_t)NE * ID * HD * 2;   // 67 MB
  unsigned short* wot = (unsigned short*)p; p += (size_t)HD * ID * 2;        // 8.4 MB
  unsigned short* xb  = (unsigned short*)p; p += (size_t)NTOK * HD * 2;      // 16.8 MB
  unsigned short* interb = (unsigned short*)p; p += (size_t)NTOK * ID * 2;   // 67 MB
  int* eidx = (int*)p; p += (size_t)NTOK * 4;
  int* perm = (int*)p; p += (size_t)NTOK * 4;
  int* ints = (int*)p;
  int* ntiles    = ints;        // 1
  int* tile_e    = ints + 8;    // 40
  int* tile_base = ints + 80;   // 40
  int* tile_len  = ints + 152;  // 40

  router_kernel<<<NTOK / 4, 256, 0, stream>>>(x, wr, eidx, xb);
  transpose_cast_kernel<<<dim3(ID / 64, HD / 64, NE), 256, 0, stream>>>(w1, w1t, HD, ID);
  transpose_cast_kernel<<<dim3(HD / 64, ID / 64, 1), 256, 0, stream>>>(wo, wot, ID, HD);
  sort_kernel<<<1, SORTT, 0, stream>>>(eidx, ntiles, tile_e, tile_base, tile_len, perm);
  init_y_kernel<<<NTOK, 256, 0, stream>>>(x, bo, out);
  ffn1_kernel<<<16 * MAXTILES, 512, 0, stream>>>(
      xb, w1t, b1, perm, ntiles, tile_e, tile_base, tile_len, interb);
  ffn2_kernel<<<512, 512, 0, stream>>>(interb, wot, out);
  ln_kernel<<<NTOK, 256, 0, stream>>>(out, gamma, beta);
}

// Round 4
// 656.955 us; speedup vs baseline: 4.4444x; 4.4444x over previous
//
#include <hip/hip_runtime.h>
#include <hip/hip_bf16.h>
#include <math.h>

#define NTOK 8192
#define HD 1024
#define ID 4096
#define NE 8
#define MAXTILES 40   // 256-row token tiles: <= 32 full + 8 partial
#define SORTT 512
#define TPT (NTOK / SORTT)  // 16 tokens per sort thread

typedef __attribute__((ext_vector_type(8))) short short8;
typedef __attribute__((ext_vector_type(8))) unsigned short ushort8;
typedef __attribute__((ext_vector_type(4))) float floatx4;

__device__ __forceinline__ unsigned short f2bf(float f) {
  unsigned int u = __float_as_uint(f);
  return (unsigned short)((u + 0x7fffu + ((u >> 16) & 1u)) >> 16);
}

__device__ __forceinline__ void async_ld16(const void* g, void* l) {
  __builtin_amdgcn_global_load_lds(
      (const __attribute__((address_space(1))) unsigned int*)g,
      (__attribute__((address_space(3))) unsigned int*)l,
      16, 0, 0);
}

// ---------------- small kernels ----------------

__global__ void transpose_cast_kernel(const float* __restrict__ src,
                                      unsigned short* __restrict__ dst, int R, int C) {
  size_t bo = (size_t)blockIdx.z * R * C;
  src += bo; dst += bo;
  __shared__ float t[64][65];
  int c0 = blockIdx.x * 64, r0 = blockIdx.y * 64;
  int tid = threadIdx.x;
  int rr = tid >> 4, c4 = (tid & 15) * 4;
#pragma unroll
  for (int q = 0; q < 4; q++) {
    int r = rr + q * 16;
    float4 v = *(const float4*)(src + (size_t)(r0 + r) * C + c0 + c4);
    t[r][c4] = v.x; t[r][c4 + 1] = v.y; t[r][c4 + 2] = v.z; t[r][c4 + 3] = v.w;
  }
  __syncthreads();
  int r8 = (tid & 7) * 8;
#pragma unroll
  for (int q = 0; q < 2; q++) {
    int cc = (tid >> 3) + q * 32;
    ushort8 o;
#pragma unroll
    for (int i = 0; i < 8; i++) o[i] = f2bf(t[r8 + i][cc]);
    *(ushort8*)(dst + (size_t)(c0 + cc) * R + r0 + r8) = o;
  }
}

__global__ void router_kernel(const float* __restrict__ x, const float* __restrict__ wr,
                              int* __restrict__ eidx, unsigned short* __restrict__ xb) {
  int wave = threadIdx.x >> 6, lane = threadIdx.x & 63;
  int n = blockIdx.x * 4 + wave;
  const float* xr = x + (size_t)n * HD;
  unsigned short* xbr = xb + (size_t)n * HD;
  double acc[NE];
#pragma unroll
  for (int e = 0; e < NE; e++) acc[e] = 0.0;
#pragma unroll
  for (int v = 0; v < 4; v++) {
    int h = (lane + v * 64) * 4;
    float4 xv = *(const float4*)(xr + h);
    ushort4 o;
    o.x = f2bf(xv.x); o.y = f2bf(xv.y); o.z = f2bf(xv.z); o.w = f2bf(xv.w);
    *(ushort4*)(xbr + h) = o;
#pragma unroll
    for (int e = 0; e < NE; e++) {
      float4 wv = *(const float4*)(wr + e * HD + h);
      acc[e] += (double)xv.x * wv.x + (double)xv.y * wv.y +
                (double)xv.z * wv.z + (double)xv.w * wv.w;
    }
  }
#pragma unroll
  for (int m = 32; m >= 1; m >>= 1) {
#pragma unroll
    for (int e = 0; e < NE; e++) acc[e] += __shfl_xor(acc[e], m, 64);
  }
  if (lane == 0) {
    int best = 0; double bv = acc[0];
#pragma unroll
    for (int e = 1; e < NE; e++) if (acc[e] > bv) { bv = acc[e]; best = e; }
    eidx[n] = best;
  }
}

// counting sort -> perm + 256-row tile table (scratch-free, proven R6/R7)
__global__ __launch_bounds__(SORTT) void sort_kernel(
    const int* __restrict__ eidx, int* __restrict__ ntiles, int* __restrict__ tile_e,
    int* __restrict__ tile_base, int* __restrict__ tile_len, int* __restrict__ perm) {
  __shared__ int h[NE][SORTT];
  __shared__ int off_sh[NE];
  __shared__ int tot[NE];
  int t = threadIdx.x;
  int wave = t >> 6, lane = t & 63;
  const int base = t * TPT;

  int4 e0 = *(const int4*)(eidx + base);
  int4 e1 = *(const int4*)(eidx + base + 4);
  int4 e2 = *(const int4*)(eidx + base + 8);
  int4 e3 = *(const int4*)(eidx + base + 12);
  int ex[TPT] = {e0.x, e0.y, e0.z, e0.w, e1.x, e1.y, e1.z, e1.w,
                 e2.x, e2.y, e2.z, e2.w, e3.x, e3.y, e3.z, e3.w};
  int cnt0 = 0, cnt1 = 0, cnt2 = 0, cnt3 = 0, cnt4 = 0, cnt5 = 0, cnt6 = 0, cnt7 = 0;
#pragma unroll
  for (int i = 0; i < TPT; i++) {
    int e = ex[i];
    cnt0 += (e == 0); cnt1 += (e == 1); cnt2 += (e == 2); cnt3 += (e == 3);
    cnt4 += (e == 4); cnt5 += (e == 5); cnt6 += (e == 6); cnt7 += (e == 7);
  }
  h[0][t] = cnt0; h[1][t] = cnt1; h[2][t] = cnt2; h[3][t] = cnt3;
  h[4][t] = cnt4; h[5][t] = cnt5; h[6][t] = cnt6; h[7][t] = cnt7;
  __syncthreads();

  {
    int e = wave;
    int v[8], s = 0;
#pragma unroll
    for (int i = 0; i < 8; i++) { v[i] = h[e][lane * 8 + i]; s += v[i]; }
    int inc = s;
#pragma unroll
    for (int d = 1; d < 64; d <<= 1) {
      int o = __shfl_up(inc, d, 64);
      if (lane >= d) inc += o;
    }
    int exc = inc - s;
#pragma unroll
    for (int i = 0; i < 8; i++) { h[e][lane * 8 + i] = exc; exc += v[i]; }
    if (lane == 63) tot[e] = inc;
  }
  __syncthreads();

  if (t == 0) {
    int s = 0, tt = 0;
    for (int e = 0; e < NE; e++) {
      off_sh[e] = s;
      int c = tot[e];
      for (int b = 0; b < c; b += 256) {
        tile_e[tt] = e;
        tile_base[tt] = s + b;
        tile_len[tt] = (c - b < 256) ? (c - b) : 256;
        tt++;
      }
      s += c;
    }
    *ntiles = tt;
  }
  __syncthreads();

  int c0c = off_sh[0] + h[0][t], c1c = off_sh[1] + h[1][t];
  int c2c = off_sh[2] + h[2][t], c3c = off_sh[3] + h[3][t];
  int c4c = off_sh[4] + h[4][t], c5c = off_sh[5] + h[5][t];
  int c6c = off_sh[6] + h[6][t], c7c = off_sh[7] + h[7][t];
#pragma unroll
  for (int i = 0; i < TPT; i++) {
    int e = ex[i];
    int pos = c0c;
    pos = (e == 1) ? c1c : pos; pos = (e == 2) ? c2c : pos;
    pos = (e == 3) ? c3c : pos; pos = (e == 4) ? c4c : pos;
    pos = (e == 5) ? c5c : pos; pos = (e == 6) ? c6c : pos;
    pos = (e == 7) ? c7c : pos;
    perm[pos] = base + i;
    c0c += (e == 0); c1c += (e == 1); c2c += (e == 2); c3c += (e == 3);
    c4c += (e == 4); c5c += (e == 5); c6c += (e == 6); c7c += (e == 7);
  }
}

// y = x + bo (residual+bias pre-init; ffn2 atomically accumulates on top)
__global__ void init_y_kernel(const float* __restrict__ x, const float* __restrict__ bo,
                              float* __restrict__ y) {
  int row = blockIdx.x, t = threadIdx.x;
  float4 xv = *(const float4*)(x + (size_t)row * HD + t * 4);
  float4 bv = *(const float4*)(bo + t * 4);
  float4 o = {xv.x + bv.x, xv.y + bv.y, xv.z + bv.z, xv.w + bv.w};
  *(float4*)(y + (size_t)row * HD + t * 4) = o;
}

// ---------------- 256x256 GEMM core, BK=64, single-buffered ----------------
// R8: R4's PROVEN loop regime (stage -> sync -> compute -> sync; cross-block
// overlap hides latency — R4 sustained 7.4 TB/s aggregate, vs 3.2 for the
// 1-block/CU lockstep R6).  Change vs R4 = tile 128->256 (halves re-reads:
// ffn1 1.09 GB -> 576 MB).  8 waves (2M x 4N), per-wave 128x64, acc[8][4].
// LDS: [row][64] bf16, 16B chunks XOR-swizzled by (row&7) — the exact
// layout measured conflict-free in R1-R4/R6.  32 KB per matrix, 64 KB/block
// -> 2 blocks/CU (16 waves/CU).  launch_bounds(512,2): VGPR cap >= 512
// under BOTH interpretations of arg2 (R7's (512,8) caused a total-spill
// catastrophe: VGPR_Count 32, 3.8 GB scratch writes).

template <int NKS>
__device__ __forceinline__ void gemm_core(
    const unsigned short* const* gA, const unsigned short* const* gB,
    unsigned short* lA, unsigned short* lB,
    int wave, int lane, floatx4 (&acc)[8][4]) {
  int c15 = lane & 15, q4 = lane >> 4, c7 = lane & 7;
  int wm = wave >> 2, wn = wave & 3;
  int sx0 = (q4 ^ c7) * 8;        // kk=0 swizzled chunk offset (shorts)
  int sx1 = ((4 + q4) ^ c7) * 8;  // kk=1
  int aoff[8], boff[4];
#pragma unroll
  for (int i = 0; i < 8; i++) aoff[i] = (wm * 128 + i * 16 + c15) * 64;
#pragma unroll
  for (int j = 0; j < 4; j++) boff[j] = (wn * 64 + j * 16 + c15) * 64;

  for (int ko = 0; ko < NKS; ++ko) {
#pragma unroll
    for (int q = 0; q < 4; q++) {
      int c = wave * 4 + q;
      async_ld16(gA[q] + ko * 64, lA + c * 512);
      async_ld16(gB[q] + ko * 64, lB + c * 512);
    }
    __syncthreads();  // implicit vmcnt(0): tile resident
    short8 a0[8], a1[8], b0[4], b1[4];
#pragma unroll
    for (int i = 0; i < 8; i++) {
      a0[i] = *(const short8*)(lA + aoff[i] + sx0);
      a1[i] = *(const short8*)(lA + aoff[i] + sx1);
    }
#pragma unroll
    for (int j = 0; j < 4; j++) {
      b0[j] = *(const short8*)(lB + boff[j] + sx0);
      b1[j] = *(const short8*)(lB + boff[j] + sx1);
    }
#pragma unroll
    for (int i = 0; i < 8; i++)
#pragma unroll
      for (int j = 0; j < 4; j++) {
        acc[i][j] = __builtin_amdgcn_mfma_f32_16x16x32_bf16(a0[i], b0[j], acc[i][j], 0, 0, 0);
        acc[i][j] = __builtin_amdgcn_mfma_f32_16x16x32_bf16(a1[i], b1[j], acc[i][j], 0, 0, 0);
      }
    __syncthreads();  // WAR: all reads done before next stage
  }
}

// ---------------- GEMM kernels ----------------

__global__ __launch_bounds__(512, 2) void ffn1_kernel(
    const unsigned short* __restrict__ xb, const unsigned short* __restrict__ w1t,
    const float* __restrict__ b1, const int* __restrict__ perm,
    const int* __restrict__ ntiles, const int* __restrict__ tile_e,
    const int* __restrict__ tile_base, const int* __restrict__ tile_len,
    unsigned short* __restrict__ interb) {
  int t = blockIdx.y;
  if (t >= *ntiles) return;
  int e = tile_e[t], base = tile_base[t], len = tile_len[t];
  int nb = blockIdx.x * 256;

  __shared__ unsigned short lA[256 * 64];  // 32 KB
  __shared__ unsigned short lB[256 * 64];  // 32 KB

  int tid = threadIdx.x;
  int wave = tid >> 6, lane = tid & 63;
  int lr = lane >> 3;
  int chunk = (lane & 7) ^ lr;  // pre-swizzled source chunk

  const unsigned short* gA[4];
  const unsigned short* gB[4];
#pragma unroll
  for (int q = 0; q < 4; q++) {
    int c = wave * 4 + q;
    int tr = c * 8 + lr;
    int token = perm[base + (tr < len ? tr : len - 1)];  // clamp tail (stores masked)
    gA[q] = xb + (size_t)token * HD + chunk * 8;
    int nr = nb + c * 8 + lr;
    gB[q] = w1t + ((size_t)e * ID + nr) * HD + chunk * 8;
  }

  floatx4 acc[8][4];
#pragma unroll
  for (int i = 0; i < 8; i++)
#pragma unroll
    for (int j = 0; j < 4; j++) acc[i][j] = (floatx4){0.f, 0.f, 0.f, 0.f};

  gemm_core<HD / 64>(gA, gB, lA, lB, wave, lane, acc);

  int c15 = lane & 15, q4 = lane >> 4;
  int wm = wave >> 2, wn = wave & 3;
#pragma unroll
  for (int i = 0; i < 8; i++) {
#pragma unroll
    for (int r = 0; r < 4; r++) {
      int tr = wm * 128 + i * 16 + q4 * 4 + r;
      if (tr >= len) continue;
      int token = perm[base + tr];
#pragma unroll
      for (int j = 0; j < 4; j++) {
        int col = nb + wn * 64 + j * 16 + c15;
        float v = acc[i][j][r] + b1[e * ID + col];
        v = 0.5f * v * (1.0f + erff(v * 0.70710678118654752f));  // exact GELU
        interb[(size_t)token * ID + col] = f2bf(v);
      }
    }
  }
}

// split-K=4 into y (= x + bo from init_y) with HW fp32 atomics.
// grid (4 nblk, 32 tm, 4 kc) = 512 blocks = 2/CU.
__global__ __launch_bounds__(512, 2) void ffn2_kernel(
    const unsigned short* __restrict__ interb, const unsigned short* __restrict__ wot,
    float* __restrict__ y) {
  int nb = blockIdx.x * 256;
  int tm = blockIdx.y;
  int kbase = blockIdx.z * (ID / 4);  // 1024-wide K chunk

  __shared__ unsigned short lA[256 * 64];
  __shared__ unsigned short lB[256 * 64];

  int tid = threadIdx.x;
  int wave = tid >> 6, lane = tid & 63;
  int lr = lane >> 3;
  int chunk = (lane & 7) ^ lr;

  const unsigned short* gA[4];
  const unsigned short* gB[4];
#pragma unroll
  for (int q = 0; q < 4; q++) {
    int c = wave * 4 + q;
    int row = tm * 256 + c * 8 + lr;
    gA[q] = interb + (size_t)row * ID + kbase + chunk * 8;
    int nr = nb + c * 8 + lr;
    gB[q] = wot + (size_t)nr * ID + kbase + chunk * 8;
  }

  floatx4 acc[8][4];
#pragma unroll
  for (int i = 0; i < 8; i++)
#pragma unroll
    for (int j = 0; j < 4; j++) acc[i][j] = (floatx4){0.f, 0.f, 0.f, 0.f};

  gemm_core<(ID / 4) / 64>(gA, gB, lA, lB, wave, lane, acc);

  int c15 = lane & 15, q4 = lane >> 4;
  int wm = wave >> 2, wn = wave & 3;
#pragma unroll
  for (int i = 0; i < 8; i++) {
#pragma unroll
    for (int r = 0; r < 4; r++) {
      int row = tm * 256 + wm * 128 + i * 16 + q4 * 4 + r;
#pragma unroll
      for (int j = 0; j < 4; j++) {
        int col = nb + wn * 64 + j * 16 + c15;
        unsafeAtomicAdd(&y[(size_t)row * HD + col], acc[i][j][r]);
      }
    }
  }
}

__global__ void ln_kernel(float* __restrict__ y, const float* __restrict__ gamma,
                          const float* __restrict__ beta) {
  int row = blockIdx.x, t = threadIdx.x;
  int lane = t & 63, wave = t >> 6;
  float* yr = y + (size_t)row * HD;
  float4 v = *(const float4*)(yr + t * 4);
  float s = v.x + v.y + v.z + v.w;
  float ss = v.x * v.x + v.y * v.y + v.z * v.z + v.w * v.w;
#pragma unroll
  for (int m = 32; m >= 1; m >>= 1) {
    s += __shfl_xor(s, m, 64);
    ss += __shfl_xor(ss, m, 64);
  }
  __shared__ float sred[4], ssred[4];
  if (lane == 0) { sred[wave] = s; ssred[wave] = ss; }
  __syncthreads();
  s = sred[0] + sred[1] + sred[2] + sred[3];
  ss = ssred[0] + ssred[1] + ssred[2] + ssred[3];
  float mu = s * (1.0f / HD);
  float var = ss * (1.0f / HD) - mu * mu;
  float rs = rsqrtf(var + 1e-12f);
  float4 g = *(const float4*)(gamma + t * 4);
  float4 b = *(const float4*)(beta + t * 4);
  float4 o;
  o.x = (v.x - mu) * rs * g.x + b.x;
  o.y = (v.y - mu) * rs * g.y + b.y;
  o.z = (v.z - mu) * rs * g.z + b.z;
  o.w = (v.w - mu) * rs * g.w + b.w;
  *(float4*)(yr + t * 4) = o;
}

// ---------------- host launcher ----------------

extern "C" void kernel_launch(void* const* d_in, const int* in_sizes, int n_in,
                              void* d_out, int out_size, void* d_ws, size_t ws_size,
                              hipStream_t stream) {
  const float* x     = (const float*)d_in[0];
  const float* wr    = (const float*)d_in[1];
  const float* w1    = (const float*)d_in[2];
  const float* b1    = (const float*)d_in[3];
  const float* wo    = (const float*)d_in[4];
  const float* bo    = (const float*)d_in[5];
  const float* gamma = (const float*)d_in[6];
  const float* beta  = (const float*)d_in[7];
  float* out = (float*)d_out;

  char* p = (char*)d_ws;
  unsigned short* w1t = (unsigned short*)p; p += (size_t)NE * ID * HD * 2;   // 67 MB
  unsigned short* wot = (unsigned short*)p; p += (size_t)HD * ID * 2;        // 8.4 MB
  unsigned short* xb  = (unsigned short*)p; p += (size_t)NTOK * HD * 2;      // 16.8 MB
  unsigned short* interb = (unsigned short*)p; p += (size_t)NTOK * ID * 2;   // 67 MB
  int* eidx = (int*)p; p += (size_t)NTOK * 4;
  int* perm = (int*)p; p += (size_t)NTOK * 4;
  int* ints = (int*)p;
  int* ntiles    = ints;        // 1
  int* tile_e    = ints + 8;    // 40
  int* tile_base = ints + 80;   // 40
  int* tile_len  = ints + 152;  // 40

  router_kernel<<<NTOK / 4, 256, 0, stream>>>(x, wr, eidx, xb);
  transpose_cast_kernel<<<dim3(ID / 64, HD / 64, NE), 256, 0, stream>>>(w1, w1t, HD, ID);
  transpose_cast_kernel<<<dim3(HD / 64, ID / 64, 1), 256, 0, stream>>>(wo, wot, ID, HD);
  sort_kernel<<<1, SORTT, 0, stream>>>(eidx, ntiles, tile_e, tile_base, tile_len, perm);
  init_y_kernel<<<NTOK, 256, 0, stream>>>(x, bo, out);
  ffn1_kernel<<<dim3(ID / 256, MAXTILES), 512, 0, stream>>>(
      xb, w1t, b1, perm, ntiles, tile_e, tile_base, tile_len, interb);
  ffn2_kernel<<<dim3(HD / 256, NTOK / 256, 4), 512, 0, stream>>>(interb, wot, out);
  ln_kernel<<<NTOK, 256, 0, stream>>>(out, gamma, beta);
}

// Round 5
// 474.303 us; speedup vs baseline: 6.1559x; 1.3851x over previous
//
#include <hip/hip_runtime.h>
#include <hip/hip_bf16.h>
#include <math.h>

#define NTOK 8192
#define HD 1024
#define ID 4096
#define NE 8
#define MAXTILES 72
#define SORTT 512
#define TPT (NTOK / SORTT)  // 16 tokens per sort thread

typedef __attribute__((ext_vector_type(8))) short short8;
typedef __attribute__((ext_vector_type(8))) unsigned short ushort8;
typedef __attribute__((ext_vector_type(4))) float floatx4;

__device__ __forceinline__ unsigned short f2bf(float f) {
  unsigned int u = __float_as_uint(f);
  return (unsigned short)((u + 0x7fffu + ((u >> 16) & 1u)) >> 16);
}

__device__ __forceinline__ void async_ld16(const void* g, void* l) {
  __builtin_amdgcn_global_load_lds(
      (const __attribute__((address_space(1))) unsigned int*)g,
      (__attribute__((address_space(3))) unsigned int*)l,
      16, 0, 0);
}

// ---------------- fused preamble: transposes + router ----------------
// One kernel so the independent pre-GEMM work fills the machine together
// instead of serializing across 3 launches.

__device__ __forceinline__ void transpose_tile(const float* __restrict__ src,
                                               unsigned short* __restrict__ dst,
                                               int R, int C, int bx, int by, int bz,
                                               float (*t)[65]) {
  size_t bo = (size_t)bz * R * C;
  src += bo; dst += bo;
  int c0 = bx * 64, r0 = by * 64;
  int tid = threadIdx.x;
  int rr = tid >> 4, c4 = (tid & 15) * 4;
#pragma unroll
  for (int q = 0; q < 4; q++) {
    int r = rr + q * 16;
    float4 v = *(const float4*)(src + (size_t)(r0 + r) * C + c0 + c4);
    t[r][c4] = v.x; t[r][c4 + 1] = v.y; t[r][c4 + 2] = v.z; t[r][c4 + 3] = v.w;
  }
  __syncthreads();
  int r8 = (tid & 7) * 8;
#pragma unroll
  for (int q = 0; q < 2; q++) {
    int cc = (tid >> 3) + q * 32;
    ushort8 o;
#pragma unroll
    for (int i = 0; i < 8; i++) o[i] = f2bf(t[r8 + i][cc]);
    *(ushort8*)(dst + (size_t)(c0 + cc) * R + r0 + r8) = o;
  }
}

__device__ __forceinline__ void router_body(const float* __restrict__ x,
                                            const float* __restrict__ wr,
                                            int* __restrict__ eidx,
                                            unsigned short* __restrict__ xb, int nbase) {
  int wave = threadIdx.x >> 6, lane = threadIdx.x & 63;
  int n = nbase + wave;
  const float* xr = x + (size_t)n * HD;
  unsigned short* xbr = xb + (size_t)n * HD;
  double acc[NE];
#pragma unroll
  for (int e = 0; e < NE; e++) acc[e] = 0.0;
#pragma unroll
  for (int v = 0; v < 4; v++) {
    int h = (lane + v * 64) * 4;
    float4 xv = *(const float4*)(xr + h);
    ushort4 o;
    o.x = f2bf(xv.x); o.y = f2bf(xv.y); o.z = f2bf(xv.z); o.w = f2bf(xv.w);
    *(ushort4*)(xbr + h) = o;
#pragma unroll
    for (int e = 0; e < NE; e++) {
      float4 wv = *(const float4*)(wr + e * HD + h);
      acc[e] += (double)xv.x * wv.x + (double)xv.y * wv.y +
                (double)xv.z * wv.z + (double)xv.w * wv.w;
    }
  }
#pragma unroll
  for (int m = 32; m >= 1; m >>= 1) {
#pragma unroll
    for (int e = 0; e < NE; e++) acc[e] += __shfl_xor(acc[e], m, 64);
  }
  if (lane == 0) {
    int best = 0; double bv = acc[0];
#pragma unroll
    for (int e = 1; e < NE; e++) if (acc[e] > bv) { bv = acc[e]; best = e; }
    eidx[n] = best;
  }
}

// grid: [0,8192) w1 transpose, [8192,9216) wo transpose, [9216,11264) router
__global__ void preamble_kernel(const float* __restrict__ x, const float* __restrict__ wr,
                                const float* __restrict__ w1, const float* __restrict__ wo,
                                unsigned short* __restrict__ w1t, unsigned short* __restrict__ wot,
                                int* __restrict__ eidx, unsigned short* __restrict__ xb) {
  __shared__ float tile[64][65];
  int b = blockIdx.x;
  if (b < 8192) {
    transpose_tile(w1, w1t, HD, ID, b & 63, (b >> 6) & 15, b >> 10, tile);
  } else if (b < 9216) {
    int bb = b - 8192;
    transpose_tile(wo, wot, ID, HD, bb & 15, bb >> 4, 0, tile);
  } else {
    router_body(x, wr, eidx, xb, (b - 9216) * 4);
  }
}

// counting sort -> perm + 128-row tile table (scratch-free, proven R1-R4)
__global__ __launch_bounds__(SORTT) void sort_kernel(
    const int* __restrict__ eidx, int* __restrict__ ntiles, int* __restrict__ tile_e,
    int* __restrict__ tile_base, int* __restrict__ tile_len, int* __restrict__ perm) {
  __shared__ int h[NE][SORTT];
  __shared__ int off_sh[NE];
  __shared__ int tot[NE];
  int t = threadIdx.x;
  int wave = t >> 6, lane = t & 63;
  const int base = t * TPT;

  int4 e0 = *(const int4*)(eidx + base);
  int4 e1 = *(const int4*)(eidx + base + 4);
  int4 e2 = *(const int4*)(eidx + base + 8);
  int4 e3 = *(const int4*)(eidx + base + 12);
  int ex[TPT] = {e0.x, e0.y, e0.z, e0.w, e1.x, e1.y, e1.z, e1.w,
                 e2.x, e2.y, e2.z, e2.w, e3.x, e3.y, e3.z, e3.w};
  int cnt0 = 0, cnt1 = 0, cnt2 = 0, cnt3 = 0, cnt4 = 0, cnt5 = 0, cnt6 = 0, cnt7 = 0;
#pragma unroll
  for (int i = 0; i < TPT; i++) {
    int e = ex[i];
    cnt0 += (e == 0); cnt1 += (e == 1); cnt2 += (e == 2); cnt3 += (e == 3);
    cnt4 += (e == 4); cnt5 += (e == 5); cnt6 += (e == 6); cnt7 += (e == 7);
  }
  h[0][t] = cnt0; h[1][t] = cnt1; h[2][t] = cnt2; h[3][t] = cnt3;
  h[4][t] = cnt4; h[5][t] = cnt5; h[6][t] = cnt6; h[7][t] = cnt7;
  __syncthreads();

  {
    int e = wave;
    int v[8], s = 0;
#pragma unroll
    for (int i = 0; i < 8; i++) { v[i] = h[e][lane * 8 + i]; s += v[i]; }
    int inc = s;
#pragma unroll
    for (int d = 1; d < 64; d <<= 1) {
      int o = __shfl_up(inc, d, 64);
      if (lane >= d) inc += o;
    }
    int exc = inc - s;
#pragma unroll
    for (int i = 0; i < 8; i++) { h[e][lane * 8 + i] = exc; exc += v[i]; }
    if (lane == 63) tot[e] = inc;
  }
  __syncthreads();

  if (t == 0) {
    int s = 0, tt = 0;
    for (int e = 0; e < NE; e++) {
      off_sh[e] = s;
      int c = tot[e];
      for (int b = 0; b < c; b += 128) {
        tile_e[tt] = e;
        tile_base[tt] = s + b;
        tile_len[tt] = (c - b < 128) ? (c - b) : 128;
        tt++;
      }
      s += c;
    }
    *ntiles = tt;
  }
  __syncthreads();

  int c0c = off_sh[0] + h[0][t], c1c = off_sh[1] + h[1][t];
  int c2c = off_sh[2] + h[2][t], c3c = off_sh[3] + h[3][t];
  int c4c = off_sh[4] + h[4][t], c5c = off_sh[5] + h[5][t];
  int c6c = off_sh[6] + h[6][t], c7c = off_sh[7] + h[7][t];
#pragma unroll
  for (int i = 0; i < TPT; i++) {
    int e = ex[i];
    int pos = c0c;
    pos = (e == 1) ? c1c : pos; pos = (e == 2) ? c2c : pos;
    pos = (e == 3) ? c3c : pos; pos = (e == 4) ? c4c : pos;
    pos = (e == 5) ? c5c : pos; pos = (e == 6) ? c6c : pos;
    pos = (e == 7) ? c7c : pos;
    perm[pos] = base + i;
    c0c += (e == 0); c1c += (e == 1); c2c += (e == 2); c3c += (e == 3);
    c4c += (e == 4); c5c += (e == 5); c6c += (e == 6); c7c += (e == 7);
  }
}

// ---------------- GEMM kernels (R4 internals, XCD-locality remap) ----------
// 128x128 tile, BK=64, 4 waves (2x2), acc[4][4], 16x16x32 bf16.  LDS
// [row][64] bf16, 16B chunks XOR-swizzled by (row&7): 0 bank conflicts
// (measured R1-R4).  stage -> sync -> compute -> sync; latency hiding comes
// from ~3-4 independent 4-wave blocks/CU (this structure sustains 8.1 TB/s
// aggregate staging — best of all structures tried R4-R8).
//
// R9 change: ONLY the blockIdx -> (tile, nblock) mapping.  HW round-robins
// blocks to XCDs (xcd = bid & 7).  We co-locate on each XCD the blocks that
// share one (expert, n-half) B-panel (4.2 MB ~ L2-sized) and one A-panel,
// turning the L3-tier B/A re-streams (the 8.1 TB/s wall) into per-XCD L2
// hits.  Bijective decode; worst case it's a no-op perf-wise.

__global__ __launch_bounds__(256, 2) void ffn1_kernel(
    const unsigned short* __restrict__ xb, const unsigned short* __restrict__ w1t,
    const float* __restrict__ b1, const int* __restrict__ perm,
    const int* __restrict__ ntiles, const int* __restrict__ tile_e,
    const int* __restrict__ tile_base, const int* __restrict__ tile_len,
    unsigned short* __restrict__ interb) {
  // grid 2304 = 8 xcd x 288 slots.  xcd covers t-quarter x n-half:
  //   slot s: 16 consecutive blocks share tile t (A-panel), t advances
  //   every 16 slots within the quarter -> concurrent working set on the
  //   XCD ~ one expert's B-half (4.2 MB) + few A-panels.
  int w = blockIdx.x;
  int x = w & 7, s = w >> 3;         // xcd, slot 0..287
  int hh = x & 1, q = x >> 1;        // n-half, t-quarter
  int t = q * 18 + (s >> 4);         // tile 0..71
  if (t >= *ntiles) return;
  int nb = (hh * 16 + (s & 15)) * 128;
  int e = tile_e[t], base = tile_base[t], len = tile_len[t];

  __shared__ unsigned short lA[128 * 64];
  __shared__ unsigned short lB[128 * 64];

  int tid = threadIdx.x;
  int wave = tid >> 6, lane = tid & 63;
  int lr = lane >> 3;              // row-within-8-row-chunk
  int chunk = (lane & 7) ^ lr;     // swizzled 16B chunk selector

  const unsigned short* gA[4];
  const unsigned short* gB[4];
#pragma unroll
  for (int qq = 0; qq < 4; qq++) {
    int c = wave * 4 + qq;
    int tr = c * 8 + lr;
    int token = perm[base + (tr < len ? tr : len - 1)];  // clamp tail (stores masked)
    gA[qq] = xb + (size_t)token * HD + chunk * 8;
    int nr = nb + c * 8 + lr;
    gB[qq] = w1t + ((size_t)e * ID + nr) * HD + chunk * 8;
  }

  floatx4 acc[4][4];
#pragma unroll
  for (int i = 0; i < 4; i++)
#pragma unroll
    for (int j = 0; j < 4; j++) acc[i][j] = (floatx4){0.f, 0.f, 0.f, 0.f};

  int wm = (wave >> 1) * 64, wn = (wave & 1) * 64;
  int c15 = lane & 15, q4 = lane >> 4;

  for (int ko = 0; ko < HD / 64; ko++) {
#pragma unroll
    for (int qq = 0; qq < 4; qq++) {
      int c = wave * 4 + qq;
      async_ld16(gA[qq] + ko * 64, &lA[c * 512]);
      async_ld16(gB[qq] + ko * 64, &lB[c * 512]);
    }
    __syncthreads();
#pragma unroll
    for (int kk = 0; kk < 2; kk++) {
      short8 af[4], bfr[4];
#pragma unroll
      for (int i = 0; i < 4; i++) {
        int m = wm + i * 16 + c15;
        int sa = (kk * 4 + q4) ^ (m & 7);
        af[i] = *(const short8*)&lA[m * 64 + sa * 8];
        int n = wn + i * 16 + c15;
        int sb = (kk * 4 + q4) ^ (n & 7);
        bfr[i] = *(const short8*)&lB[n * 64 + sb * 8];
      }
#pragma unroll
      for (int i = 0; i < 4; i++)
#pragma unroll
        for (int j = 0; j < 4; j++)
          acc[i][j] = __builtin_amdgcn_mfma_f32_16x16x32_bf16(af[i], bfr[j], acc[i][j], 0, 0, 0);
    }
    __syncthreads();
  }

#pragma unroll
  for (int i = 0; i < 4; i++) {
#pragma unroll
    for (int r = 0; r < 4; r++) {
      int tr = wm + i * 16 + q4 * 4 + r;
      if (tr >= len) continue;
      int token = perm[base + tr];
#pragma unroll
      for (int j = 0; j < 4; j++) {
        int col = nb + wn + j * 16 + c15;
        float v = acc[i][j][r] + b1[e * ID + col];
        v = 0.5f * v * (1.0f + erff(v * 0.70710678118654752f));  // exact GELU
        interb[(size_t)token * ID + col] = f2bf(v);
      }
    }
  }
}

// full-K ffn2, fused bias + residual; writes pre-LN y (fp32) to d_out.
__global__ __launch_bounds__(256, 2) void ffn2_kernel(
    const unsigned short* __restrict__ interb, const unsigned short* __restrict__ wot,
    const float* __restrict__ bo, const float* __restrict__ x, float* __restrict__ y) {
  // grid 512 = 8 xcd x 64 slots.  xcd = m-quarter x n-half: its 4.2 MB
  // wot-half goes L2-resident; each A-panel is shared by its 4 consecutive
  // n-blocks (concurrent) and fetched ~once per half instead of 8x.
  int w = blockIdx.x;
  int x8 = w & 7, s = w >> 3;        // xcd, slot 0..63
  int mq = x8 >> 1, nh = x8 & 1;
  int tm = mq * 16 + (s >> 2);       // m-tile 0..63
  int nb = (nh * 4 + (s & 3)) * 128; // n-block

  __shared__ unsigned short lA[128 * 64];
  __shared__ unsigned short lB[128 * 64];

  int tid = threadIdx.x;
  int wave = tid >> 6, lane = tid & 63;
  int lr = lane >> 3;
  int chunk = (lane & 7) ^ lr;

  const unsigned short* gA[4];
  const unsigned short* gB[4];
#pragma unroll
  for (int qq = 0; qq < 4; qq++) {
    int c = wave * 4 + qq;
    int row = tm * 128 + c * 8 + lr;
    gA[qq] = interb + (size_t)row * ID + chunk * 8;
    int nr = nb + c * 8 + lr;
    gB[qq] = wot + (size_t)nr * ID + chunk * 8;
  }

  floatx4 acc[4][4];
#pragma unroll
  for (int i = 0; i < 4; i++)
#pragma unroll
    for (int j = 0; j < 4; j++) acc[i][j] = (floatx4){0.f, 0.f, 0.f, 0.f};

  int wm = (wave >> 1) * 64, wn = (wave & 1) * 64;
  int c15 = lane & 15, q4 = lane >> 4;

  for (int ko = 0; ko < ID / 64; ko++) {
#pragma unroll
    for (int qq = 0; qq < 4; qq++) {
      int c = wave * 4 + qq;
      async_ld16(gA[qq] + ko * 64, &lA[c * 512]);
      async_ld16(gB[qq] + ko * 64, &lB[c * 512]);
    }
    __syncthreads();
#pragma unroll
    for (int kk = 0; kk < 2; kk++) {
      short8 af[4], bfr[4];
#pragma unroll
      for (int i = 0; i < 4; i++) {
        int m = wm + i * 16 + c15;
        int sa = (kk * 4 + q4) ^ (m & 7);
        af[i] = *(const short8*)&lA[m * 64 + sa * 8];
        int n = wn + i * 16 + c15;
        int sb = (kk * 4 + q4) ^ (n & 7);
        bfr[i] = *(const short8*)&lB[n * 64 + sb * 8];
      }
#pragma unroll
      for (int i = 0; i < 4; i++)
#pragma unroll
        for (int j = 0; j < 4; j++)
          acc[i][j] = __builtin_amdgcn_mfma_f32_16x16x32_bf16(af[i], bfr[j], acc[i][j], 0, 0, 0);
    }
    __syncthreads();
  }

#pragma unroll
  for (int i = 0; i < 4; i++) {
#pragma unroll
    for (int r = 0; r < 4; r++) {
      int row = tm * 128 + wm + i * 16 + q4 * 4 + r;
#pragma unroll
      for (int j = 0; j < 4; j++) {
        int col = nb + wn + j * 16 + c15;
        float v = acc[i][j][r] + bo[col] + x[(size_t)row * HD + col];
        y[(size_t)row * HD + col] = v;  // pre-LN y staged in d_out
      }
    }
  }
}

__global__ void ln_kernel(float* __restrict__ y, const float* __restrict__ gamma,
                          const float* __restrict__ beta) {
  int row = blockIdx.x, t = threadIdx.x;
  int lane = t & 63, wave = t >> 6;
  float* yr = y + (size_t)row * HD;
  float4 v = *(const float4*)(yr + t * 4);
  float s = v.x + v.y + v.z + v.w;
  float ss = v.x * v.x + v.y * v.y + v.z * v.z + v.w * v.w;
#pragma unroll
  for (int m = 32; m >= 1; m >>= 1) {
    s += __shfl_xor(s, m, 64);
    ss += __shfl_xor(ss, m, 64);
  }
  __shared__ float sred[4], ssred[4];
  if (lane == 0) { sred[wave] = s; ssred[wave] = ss; }
  __syncthreads();
  s = sred[0] + sred[1] + sred[2] + sred[3];
  ss = ssred[0] + ssred[1] + ssred[2] + ssred[3];
  float mu = s * (1.0f / HD);
  float var = ss * (1.0f / HD) - mu * mu;
  float rs = rsqrtf(var + 1e-12f);
  float4 g = *(const float4*)(gamma + t * 4);
  float4 b = *(const float4*)(beta + t * 4);
  float4 o;
  o.x = (v.x - mu) * rs * g.x + b.x;
  o.y = (v.y - mu) * rs * g.y + b.y;
  o.z = (v.z - mu) * rs * g.z + b.z;
  o.w = (v.w - mu) * rs * g.w + b.w;
  *(float4*)(yr + t * 4) = o;
}

// ---------------- host launcher ----------------

extern "C" void kernel_launch(void* const* d_in, const int* in_sizes, int n_in,
                              void* d_out, int out_size, void* d_ws, size_t ws_size,
                              hipStream_t stream) {
  const float* x     = (const float*)d_in[0];
  const float* wr    = (const float*)d_in[1];
  const float* w1    = (const float*)d_in[2];
  const float* b1    = (const float*)d_in[3];
  const float* wo    = (const float*)d_in[4];
  const float* bo    = (const float*)d_in[5];
  const float* gamma = (const float*)d_in[6];
  const float* beta  = (const float*)d_in[7];
  float* out = (float*)d_out;

  char* p = (char*)d_ws;
  unsigned short* w1t = (unsigned short*)p; p += (size_t)NE * ID * HD * 2;   // 67 MB
  unsigned short* wot = (unsigned short*)p; p += (size_t)HD * ID * 2;        // 8.4 MB
  unsigned short* xb  = (unsigned short*)p; p += (size_t)NTOK * HD * 2;      // 16.8 MB
  unsigned short* interb = (unsigned short*)p; p += (size_t)NTOK * ID * 2;   // 67 MB
  int* eidx = (int*)p; p += (size_t)NTOK * 4;
  int* perm = (int*)p; p += (size_t)NTOK * 4;
  int* ints = (int*)p;
  int* ntiles    = ints;        // 1
  int* tile_e    = ints + 8;    // 72
  int* tile_base = ints + 80;   // 72
  int* tile_len  = ints + 152;  // 72

  preamble_kernel<<<11264, 256, 0, stream>>>(x, wr, w1, wo, w1t, wot, eidx, xb);
  sort_kernel<<<1, SORTT, 0, stream>>>(eidx, ntiles, tile_e, tile_base, tile_len, perm);
  ffn1_kernel<<<2304, 256, 0, stream>>>(
      xb, w1t, b1, perm, ntiles, tile_e, tile_base, tile_len, interb);
  ffn2_kernel<<<512, 256, 0, stream>>>(interb, wot, bo, x, out);
  ln_kernel<<<NTOK, 256, 0, stream>>>(out, gamma, beta);
}

// Round 6
// 472.916 us; speedup vs baseline: 6.1740x; 1.0029x over previous
//
#include <hip/hip_runtime.h>
#include <hip/hip_bf16.h>
#include <math.h>

#define NTOK 8192
#define HD 1024
#define ID 4096
#define NE 8
#define MAXTILES 72
#define SORTT 512
#define TPT (NTOK / SORTT)  // 16 tokens per sort thread

typedef __attribute__((ext_vector_type(8))) short short8;
typedef __attribute__((ext_vector_type(8))) unsigned short ushort8;
typedef __attribute__((ext_vector_type(4))) float floatx4;

__device__ __forceinline__ unsigned short f2bf(float f) {
  unsigned int u = __float_as_uint(f);
  return (unsigned short)((u + 0x7fffu + ((u >> 16) & 1u)) >> 16);
}

__device__ __forceinline__ void async_ld16(const void* g, void* l) {
  __builtin_amdgcn_global_load_lds(
      (const __attribute__((address_space(1))) unsigned int*)g,
      (__attribute__((address_space(3))) unsigned int*)l,
      16, 0, 0);
}

// ---------------- fused preamble: transposes + router ----------------
// R10: 256x64 transpose tile (was 64x64).  Output rows now carry 256
// shorts = 512 B contiguous per 32-lane group (4x the old 128 B segments
// -- the old kernel ran at 1 TB/s with 2% VALU: pure HBM-transaction
// inefficiency).  LDS staged as bf16 [256][72] (36.9 KB, 4 blocks/CU)
// with 8B-granule XOR swizzle (g ^= (row>>3)&15):
//   phase-1 8B stores: 4 dwords/bank uniform  = conflict-free minimum
//   phase-2 u16 reads: 2 lanes/bank           = free (m136)

__device__ __forceinline__ void transpose_tile256(const float* __restrict__ src,
                                                  unsigned short* __restrict__ dst,
                                                  int R, int C, int bx, int by, int bz,
                                                  unsigned short (*t)[72]) {
  size_t bo = (size_t)bz * R * C;
  src += bo; dst += bo;
  int c0 = bx * 64, r0 = by * 256;
  int tid = threadIdx.x;
  int rr = tid >> 4, cc = tid & 15;
#pragma unroll
  for (int p = 0; p < 16; p++) {
    int r = p * 16 + rr;
    float4 v = *(const float4*)(src + (size_t)(r0 + r) * C + c0 + cc * 4);
    int gs = cc ^ ((r >> 3) & 15);
    ushort4 o;
    o.x = f2bf(v.x); o.y = f2bf(v.y); o.z = f2bf(v.z); o.w = f2bf(v.w);
    *(ushort4*)&t[r][gs * 4] = o;
  }
  __syncthreads();
  int rc = tid & 31;   // 16B r-chunk: rows rc*8..rc*8+7
  int cb = tid >> 5;   // output-row sub-index
#pragma unroll
  for (int p = 0; p < 8; p++) {
    int c = p * 8 + cb;
    int col = ((c >> 2) ^ (rc & 15)) * 4 + (c & 3);  // inverse of gs swizzle
    ushort8 o;
#pragma unroll
    for (int i = 0; i < 8; i++) o[i] = t[rc * 8 + i][col];
    *(ushort8*)(dst + (size_t)(c0 + c) * R + r0 + rc * 8) = o;
  }
}

__device__ __forceinline__ void router_body(const float* __restrict__ x,
                                            const float* __restrict__ wr,
                                            int* __restrict__ eidx,
                                            unsigned short* __restrict__ xb, int nbase) {
  int wave = threadIdx.x >> 6, lane = threadIdx.x & 63;
  int n = nbase + wave;
  const float* xr = x + (size_t)n * HD;
  unsigned short* xbr = xb + (size_t)n * HD;
  double acc[NE];
#pragma unroll
  for (int e = 0; e < NE; e++) acc[e] = 0.0;
#pragma unroll
  for (int v = 0; v < 4; v++) {
    int h = (lane + v * 64) * 4;
    float4 xv = *(const float4*)(xr + h);
    ushort4 o;
    o.x = f2bf(xv.x); o.y = f2bf(xv.y); o.z = f2bf(xv.z); o.w = f2bf(xv.w);
    *(ushort4*)(xbr + h) = o;
#pragma unroll
    for (int e = 0; e < NE; e++) {
      float4 wv = *(const float4*)(wr + e * HD + h);
      acc[e] += (double)xv.x * wv.x + (double)xv.y * wv.y +
                (double)xv.z * wv.z + (double)xv.w * wv.w;
    }
  }
#pragma unroll
  for (int m = 32; m >= 1; m >>= 1) {
#pragma unroll
    for (int e = 0; e < NE; e++) acc[e] += __shfl_xor(acc[e], m, 64);
  }
  if (lane == 0) {
    int best = 0; double bv = acc[0];
#pragma unroll
    for (int e = 1; e < NE; e++) if (acc[e] > bv) { bv = acc[e]; best = e; }
    eidx[n] = best;
  }
}

// grid 4352: [0,2048) w1 transpose (8 experts x 64 c-chunks x 4 r-chunks),
// [2048,2304) wo transpose (16 x 16), [2304,4352) router (2048 x 4 tokens)
__global__ void preamble_kernel(const float* __restrict__ x, const float* __restrict__ wr,
                                const float* __restrict__ w1, const float* __restrict__ wo,
                                unsigned short* __restrict__ w1t, unsigned short* __restrict__ wot,
                                int* __restrict__ eidx, unsigned short* __restrict__ xb) {
  __shared__ unsigned short tile[256][72];
  int b = blockIdx.x;
  if (b < 2048) {
    int e = b >> 8, rem = b & 255;
    transpose_tile256(w1, w1t, HD, ID, rem & 63, rem >> 6, e, tile);
  } else if (b < 2304) {
    int bb = b - 2048;
    transpose_tile256(wo, wot, ID, HD, bb & 15, bb >> 4, 0, tile);
  } else {
    router_body(x, wr, eidx, xb, (b - 2304) * 4);
  }
}

// counting sort -> perm + 128-row tile table (scratch-free, proven R1-R4)
__global__ __launch_bounds__(SORTT) void sort_kernel(
    const int* __restrict__ eidx, int* __restrict__ ntiles, int* __restrict__ tile_e,
    int* __restrict__ tile_base, int* __restrict__ tile_len, int* __restrict__ perm) {
  __shared__ int h[NE][SORTT];
  __shared__ int off_sh[NE];
  __shared__ int tot[NE];
  int t = threadIdx.x;
  int wave = t >> 6, lane = t & 63;
  const int base = t * TPT;

  int4 e0 = *(const int4*)(eidx + base);
  int4 e1 = *(const int4*)(eidx + base + 4);
  int4 e2 = *(const int4*)(eidx + base + 8);
  int4 e3 = *(const int4*)(eidx + base + 12);
  int ex[TPT] = {e0.x, e0.y, e0.z, e0.w, e1.x, e1.y, e1.z, e1.w,
                 e2.x, e2.y, e2.z, e2.w, e3.x, e3.y, e3.z, e3.w};
  int cnt0 = 0, cnt1 = 0, cnt2 = 0, cnt3 = 0, cnt4 = 0, cnt5 = 0, cnt6 = 0, cnt7 = 0;
#pragma unroll
  for (int i = 0; i < TPT; i++) {
    int e = ex[i];
    cnt0 += (e == 0); cnt1 += (e == 1); cnt2 += (e == 2); cnt3 += (e == 3);
    cnt4 += (e == 4); cnt5 += (e == 5); cnt6 += (e == 6); cnt7 += (e == 7);
  }
  h[0][t] = cnt0; h[1][t] = cnt1; h[2][t] = cnt2; h[3][t] = cnt3;
  h[4][t] = cnt4; h[5][t] = cnt5; h[6][t] = cnt6; h[7][t] = cnt7;
  __syncthreads();

  {
    int e = wave;
    int v[8], s = 0;
#pragma unroll
    for (int i = 0; i < 8; i++) { v[i] = h[e][lane * 8 + i]; s += v[i]; }
    int inc = s;
#pragma unroll
    for (int d = 1; d < 64; d <<= 1) {
      int o = __shfl_up(inc, d, 64);
      if (lane >= d) inc += o;
    }
    int exc = inc - s;
#pragma unroll
    for (int i = 0; i < 8; i++) { h[e][lane * 8 + i] = exc; exc += v[i]; }
    if (lane == 63) tot[e] = inc;
  }
  __syncthreads();

  if (t == 0) {
    int s = 0, tt = 0;
    for (int e = 0; e < NE; e++) {
      off_sh[e] = s;
      int c = tot[e];
      for (int b = 0; b < c; b += 128) {
        tile_e[tt] = e;
        tile_base[tt] = s + b;
        tile_len[tt] = (c - b < 128) ? (c - b) : 128;
        tt++;
      }
      s += c;
    }
    *ntiles = tt;
  }
  __syncthreads();

  int c0c = off_sh[0] + h[0][t], c1c = off_sh[1] + h[1][t];
  int c2c = off_sh[2] + h[2][t], c3c = off_sh[3] + h[3][t];
  int c4c = off_sh[4] + h[4][t], c5c = off_sh[5] + h[5][t];
  int c6c = off_sh[6] + h[6][t], c7c = off_sh[7] + h[7][t];
#pragma unroll
  for (int i = 0; i < TPT; i++) {
    int e = ex[i];
    int pos = c0c;
    pos = (e == 1) ? c1c : pos; pos = (e == 2) ? c2c : pos;
    pos = (e == 3) ? c3c : pos; pos = (e == 4) ? c4c : pos;
    pos = (e == 5) ? c5c : pos; pos = (e == 6) ? c6c : pos;
    pos = (e == 7) ? c7c : pos;
    perm[pos] = base + i;
    c0c += (e == 0); c1c += (e == 1); c2c += (e == 2); c3c += (e == 3);
    c4c += (e == 4); c5c += (e == 5); c6c += (e == 6); c7c += (e == 7);
  }
}

// ---------------- GEMM kernels (R9: R4 internals + XCD-locality remap) ----
// 128x128 tile, BK=64, 4 waves (2x2), acc[4][4], 16x16x32 bf16.  LDS
// [row][64] bf16, 16B chunks XOR-swizzled by (row&7): 0 bank conflicts.
// stage -> sync -> compute -> sync; latency hiding from ~3-4 independent
// 4-wave blocks/CU (sustains ~8 TB/s aggregate staging).  XCD remap
// (R9, measured +22% on ffn1): co-locate on each XCD the blocks sharing
// one (expert, n-half) B-panel (~4.2 MB ~ L2-sized) and one A-panel.

__global__ __launch_bounds__(256, 2) void ffn1_kernel(
    const unsigned short* __restrict__ xb, const unsigned short* __restrict__ w1t,
    const float* __restrict__ b1, const int* __restrict__ perm,
    const int* __restrict__ ntiles, const int* __restrict__ tile_e,
    const int* __restrict__ tile_base, const int* __restrict__ tile_len,
    unsigned short* __restrict__ interb) {
  // grid 2304 = 8 xcd x 288 slots.  xcd covers t-quarter x n-half.
  int w = blockIdx.x;
  int x = w & 7, s = w >> 3;         // xcd, slot 0..287
  int hh = x & 1, q = x >> 1;        // n-half, t-quarter
  int t = q * 18 + (s >> 4);         // tile 0..71
  if (t >= *ntiles) return;
  int nb = (hh * 16 + (s & 15)) * 128;
  int e = tile_e[t], base = tile_base[t], len = tile_len[t];

  __shared__ unsigned short lA[128 * 64];
  __shared__ unsigned short lB[128 * 64];

  int tid = threadIdx.x;
  int wave = tid >> 6, lane = tid & 63;
  int lr = lane >> 3;              // row-within-8-row-chunk
  int chunk = (lane & 7) ^ lr;     // swizzled 16B chunk selector

  const unsigned short* gA[4];
  const unsigned short* gB[4];
#pragma unroll
  for (int qq = 0; qq < 4; qq++) {
    int c = wave * 4 + qq;
    int tr = c * 8 + lr;
    int token = perm[base + (tr < len ? tr : len - 1)];  // clamp tail (stores masked)
    gA[qq] = xb + (size_t)token * HD + chunk * 8;
    int nr = nb + c * 8 + lr;
    gB[qq] = w1t + ((size_t)e * ID + nr) * HD + chunk * 8;
  }

  floatx4 acc[4][4];
#pragma unroll
  for (int i = 0; i < 4; i++)
#pragma unroll
    for (int j = 0; j < 4; j++) acc[i][j] = (floatx4){0.f, 0.f, 0.f, 0.f};

  int wm = (wave >> 1) * 64, wn = (wave & 1) * 64;
  int c15 = lane & 15, q4 = lane >> 4;

  for (int ko = 0; ko < HD / 64; ko++) {
#pragma unroll
    for (int qq = 0; qq < 4; qq++) {
      int c = wave * 4 + qq;
      async_ld16(gA[qq] + ko * 64, &lA[c * 512]);
      async_ld16(gB[qq] + ko * 64, &lB[c * 512]);
    }
    __syncthreads();
#pragma unroll
    for (int kk = 0; kk < 2; kk++) {
      short8 af[4], bfr[4];
#pragma unroll
      for (int i = 0; i < 4; i++) {
        int m = wm + i * 16 + c15;
        int sa = (kk * 4 + q4) ^ (m & 7);
        af[i] = *(const short8*)&lA[m * 64 + sa * 8];
        int n = wn + i * 16 + c15;
        int sb = (kk * 4 + q4) ^ (n & 7);
        bfr[i] = *(const short8*)&lB[n * 64 + sb * 8];
      }
#pragma unroll
      for (int i = 0; i < 4; i++)
#pragma unroll
        for (int j = 0; j < 4; j++)
          acc[i][j] = __builtin_amdgcn_mfma_f32_16x16x32_bf16(af[i], bfr[j], acc[i][j], 0, 0, 0);
    }
    __syncthreads();
  }

#pragma unroll
  for (int i = 0; i < 4; i++) {
#pragma unroll
    for (int r = 0; r < 4; r++) {
      int tr = wm + i * 16 + q4 * 4 + r;
      if (tr >= len) continue;
      int token = perm[base + tr];
#pragma unroll
      for (int j = 0; j < 4; j++) {
        int col = nb + wn + j * 16 + c15;
        float v = acc[i][j][r] + b1[e * ID + col];
        v = 0.5f * v * (1.0f + erff(v * 0.70710678118654752f));  // exact GELU
        interb[(size_t)token * ID + col] = f2bf(v);
      }
    }
  }
}

// full-K ffn2, fused bias + residual; writes pre-LN y (fp32) to d_out.
__global__ __launch_bounds__(256, 2) void ffn2_kernel(
    const unsigned short* __restrict__ interb, const unsigned short* __restrict__ wot,
    const float* __restrict__ bo, const float* __restrict__ x, float* __restrict__ y) {
  // grid 512 = 8 xcd x 64 slots.  xcd = m-quarter x n-half.
  int w = blockIdx.x;
  int x8 = w & 7, s = w >> 3;        // xcd, slot 0..63
  int mq = x8 >> 1, nh = x8 & 1;
  int tm = mq * 16 + (s >> 2);       // m-tile 0..63
  int nb = (nh * 4 + (s & 3)) * 128; // n-block

  __shared__ unsigned short lA[128 * 64];
  __shared__ unsigned short lB[128 * 64];

  int tid = threadIdx.x;
  int wave = tid >> 6, lane = tid & 63;
  int lr = lane >> 3;
  int chunk = (lane & 7) ^ lr;

  const unsigned short* gA[4];
  const unsigned short* gB[4];
#pragma unroll
  for (int qq = 0; qq < 4; qq++) {
    int c = wave * 4 + qq;
    int row = tm * 128 + c * 8 + lr;
    gA[qq] = interb + (size_t)row * ID + chunk * 8;
    int nr = nb + c * 8 + lr;
    gB[qq] = wot + (size_t)nr * ID + chunk * 8;
  }

  floatx4 acc[4][4];
#pragma unroll
  for (int i = 0; i < 4; i++)
#pragma unroll
    for (int j = 0; j < 4; j++) acc[i][j] = (floatx4){0.f, 0.f, 0.f, 0.f};

  int wm = (wave >> 1) * 64, wn = (wave & 1) * 64;
  int c15 = lane & 15, q4 = lane >> 4;

  for (int ko = 0; ko < ID / 64; ko++) {
#pragma unroll
    for (int qq = 0; qq < 4; qq++) {
      int c = wave * 4 + qq;
      async_ld16(gA[qq] + ko * 64, &lA[c * 512]);
      async_ld16(gB[qq] + ko * 64, &lB[c * 512]);
    }
    __syncthreads();
#pragma unroll
    for (int kk = 0; kk < 2; kk++) {
      short8 af[4], bfr[4];
#pragma unroll
      for (int i = 0; i < 4; i++) {
        int m = wm + i * 16 + c15;
        int sa = (kk * 4 + q4) ^ (m & 7);
        af[i] = *(const short8*)&lA[m * 64 + sa * 8];
        int n = wn + i * 16 + c15;
        int sb = (kk * 4 + q4) ^ (n & 7);
        bfr[i] = *(const short8*)&lB[n * 64 + sb * 8];
      }
#pragma unroll
      for (int i = 0; i < 4; i++)
#pragma unroll
        for (int j = 0; j < 4; j++)
          acc[i][j] = __builtin_amdgcn_mfma_f32_16x16x32_bf16(af[i], bfr[j], acc[i][j], 0, 0, 0);
    }
    __syncthreads();
  }

#pragma unroll
  for (int i = 0; i < 4; i++) {
#pragma unroll
    for (int r = 0; r < 4; r++) {
      int row = tm * 128 + wm + i * 16 + q4 * 4 + r;
#pragma unroll
      for (int j = 0; j < 4; j++) {
        int col = nb + wn + j * 16 + c15;
        float v = acc[i][j][r] + bo[col] + x[(size_t)row * HD + col];
        y[(size_t)row * HD + col] = v;  // pre-LN y staged in d_out
      }
    }
  }
}

__global__ void ln_kernel(float* __restrict__ y, const float* __restrict__ gamma,
                          const float* __restrict__ beta) {
  int row = blockIdx.x, t = threadIdx.x;
  int lane = t & 63, wave = t >> 6;
  float* yr = y + (size_t)row * HD;
  float4 v = *(const float4*)(yr + t * 4);
  float s = v.x + v.y + v.z + v.w;
  float ss = v.x * v.x + v.y * v.y + v.z * v.z + v.w * v.w;
#pragma unroll
  for (int m = 32; m >= 1; m >>= 1) {
    s += __shfl_xor(s, m, 64);
    ss += __shfl_xor(ss, m, 64);
  }
  __shared__ float sred[4], ssred[4];
  if (lane == 0) { sred[wave] = s; ssred[wave] = ss; }
  __syncthreads();
  s = sred[0] + sred[1] + sred[2] + sred[3];
  ss = ssred[0] + ssred[1] + ssred[2] + ssred[3];
  float mu = s * (1.0f / HD);
  float var = ss * (1.0f / HD) - mu * mu;
  float rs = rsqrtf(var + 1e-12f);
  float4 g = *(const float4*)(gamma + t * 4);
  float4 b = *(const float4*)(beta + t * 4);
  float4 o;
  o.x = (v.x - mu) * rs * g.x + b.x;
  o.y = (v.y - mu) * rs * g.y + b.y;
  o.z = (v.z - mu) * rs * g.z + b.z;
  o.w = (v.w - mu) * rs * g.w + b.w;
  *(float4*)(yr + t * 4) = o;
}

// ---------------- host launcher ----------------

extern "C" void kernel_launch(void* const* d_in, const int* in_sizes, int n_in,
                              void* d_out, int out_size, void* d_ws, size_t ws_size,
                              hipStream_t stream) {
  const float* x     = (const float*)d_in[0];
  const float* wr    = (const float*)d_in[1];
  const float* w1    = (const float*)d_in[2];
  const float* b1    = (const float*)d_in[3];
  const float* wo    = (const float*)d_in[4];
  const float* bo    = (const float*)d_in[5];
  const float* gamma = (const float*)d_in[6];
  const float* beta  = (const float*)d_in[7];
  float* out = (float*)d_out;

  char* p = (char*)d_ws;
  unsigned short* w1t = (unsigned short*)p; p += (size_t)NE * ID * HD * 2;   // 67 MB
  unsigned short* wot = (unsigned short*)p; p += (size_t)HD * ID * 2;        // 8.4 MB
  unsigned short* xb  = (unsigned short*)p; p += (size_t)NTOK * HD * 2;      // 16.8 MB
  unsigned short* interb = (unsigned short*)p; p += (size_t)NTOK * ID * 2;   // 67 MB
  int* eidx = (int*)p; p += (size_t)NTOK * 4;
  int* perm = (int*)p; p += (size_t)NTOK * 4;
  int* ints = (int*)p;
  int* ntiles    = ints;        // 1
  int* tile_e    = ints + 8;    // 72
  int* tile_base = ints + 80;   // 72
  int* tile_len  = ints + 152;  // 72

  preamble_kernel<<<4352, 256, 0, stream>>>(x, wr, w1, wo, w1t, wot, eidx, xb);
  sort_kernel<<<1, SORTT, 0, stream>>>(eidx, ntiles, tile_e, tile_base, tile_len, perm);
  ffn1_kernel<<<2304, 256, 0, stream>>>(
      xb, w1t, b1, perm, ntiles, tile_e, tile_base, tile_len, interb);
  ffn2_kernel<<<512, 256, 0, stream>>>(interb, wot, bo, x, out);
  ln_kernel<<<NTOK, 256, 0, stream>>>(out, gamma, beta);
}

// Round 7
// 468.710 us; speedup vs baseline: 6.2294x; 1.0090x over previous
//
#include <hip/hip_runtime.h>
#include <hip/hip_bf16.h>
#include <math.h>

#define NTOK 8192
#define HD 1024
#define ID 4096
#define NE 8
#define MAXTILES 72
#define SORTT 512
#define TPT (NTOK / SORTT)  // 16 tokens per sort thread

typedef __attribute__((ext_vector_type(8))) short short8;
typedef __attribute__((ext_vector_type(8))) unsigned short ushort8;
typedef __attribute__((ext_vector_type(4))) float floatx4;

__device__ __forceinline__ unsigned short f2bf(float f) {
  unsigned int u = __float_as_uint(f);
  return (unsigned short)((u + 0x7fffu + ((u >> 16) & 1u)) >> 16);
}

__device__ __forceinline__ void async_ld16(const void* g, void* l) {
  __builtin_amdgcn_global_load_lds(
      (const __attribute__((address_space(1))) unsigned int*)g,
      (__attribute__((address_space(3))) unsigned int*)l,
      16, 0, 0);
}

// ---------------- fused preamble: transposes + router ----------------
// R10 256x64 transpose tile: output rows carry 512 B contiguous per
// 32-lane group; LDS bf16 [256][72] with 8B-granule XOR swizzle
// (phase-1 stores conflict-free, phase-2 reads 2-way = free).

__device__ __forceinline__ void transpose_tile256(const float* __restrict__ src,
                                                  unsigned short* __restrict__ dst,
                                                  int R, int C, int bx, int by, int bz,
                                                  unsigned short (*t)[72]) {
  size_t bo = (size_t)bz * R * C;
  src += bo; dst += bo;
  int c0 = bx * 64, r0 = by * 256;
  int tid = threadIdx.x;
  int rr = tid >> 4, cc = tid & 15;
#pragma unroll
  for (int p = 0; p < 16; p++) {
    int r = p * 16 + rr;
    float4 v = *(const float4*)(src + (size_t)(r0 + r) * C + c0 + cc * 4);
    int gs = cc ^ ((r >> 3) & 15);
    ushort4 o;
    o.x = f2bf(v.x); o.y = f2bf(v.y); o.z = f2bf(v.z); o.w = f2bf(v.w);
    *(ushort4*)&t[r][gs * 4] = o;
  }
  __syncthreads();
  int rc = tid & 31;   // 16B r-chunk: rows rc*8..rc*8+7
  int cb = tid >> 5;   // output-row sub-index
#pragma unroll
  for (int p = 0; p < 8; p++) {
    int c = p * 8 + cb;
    int col = ((c >> 2) ^ (rc & 15)) * 4 + (c & 3);  // inverse of gs swizzle
    ushort8 o;
#pragma unroll
    for (int i = 0; i < 8; i++) o[i] = t[rc * 8 + i][col];
    *(ushort8*)(dst + (size_t)(c0 + c) * R + r0 + rc * 8) = o;
  }
}

__device__ __forceinline__ void router_body(const float* __restrict__ x,
                                            const float* __restrict__ wr,
                                            int* __restrict__ eidx,
                                            unsigned short* __restrict__ xb, int nbase) {
  int wave = threadIdx.x >> 6, lane = threadIdx.x & 63;
  int n = nbase + wave;
  const float* xr = x + (size_t)n * HD;
  unsigned short* xbr = xb + (size_t)n * HD;
  double acc[NE];
#pragma unroll
  for (int e = 0; e < NE; e++) acc[e] = 0.0;
#pragma unroll
  for (int v = 0; v < 4; v++) {
    int h = (lane + v * 64) * 4;
    float4 xv = *(const float4*)(xr + h);
    ushort4 o;
    o.x = f2bf(xv.x); o.y = f2bf(xv.y); o.z = f2bf(xv.z); o.w = f2bf(xv.w);
    *(ushort4*)(xbr + h) = o;
#pragma unroll
    for (int e = 0; e < NE; e++) {
      float4 wv = *(const float4*)(wr + e * HD + h);
      acc[e] += (double)xv.x * wv.x + (double)xv.y * wv.y +
                (double)xv.z * wv.z + (double)xv.w * wv.w;
    }
  }
#pragma unroll
  for (int m = 32; m >= 1; m >>= 1) {
#pragma unroll
    for (int e = 0; e < NE; e++) acc[e] += __shfl_xor(acc[e], m, 64);
  }
  if (lane == 0) {
    int best = 0; double bv = acc[0];
#pragma unroll
    for (int e = 1; e < NE; e++) if (acc[e] > bv) { bv = acc[e]; best = e; }
    eidx[n] = best;
  }
}

// grid 4352: [0,2048) w1 transpose (8 experts x 64 c-chunks x 4 r-chunks),
// [2048,2304) wo transpose (16 x 16), [2304,4352) router (2048 x 4 tokens)
__global__ void preamble_kernel(const float* __restrict__ x, const float* __restrict__ wr,
                                const float* __restrict__ w1, const float* __restrict__ wo,
                                unsigned short* __restrict__ w1t, unsigned short* __restrict__ wot,
                                int* __restrict__ eidx, unsigned short* __restrict__ xb) {
  __shared__ unsigned short tile[256][72];
  int b = blockIdx.x;
  if (b < 2048) {
    int e = b >> 8, rem = b & 255;
    transpose_tile256(w1, w1t, HD, ID, rem & 63, rem >> 6, e, tile);
  } else if (b < 2304) {
    int bb = b - 2048;
    transpose_tile256(wo, wot, ID, HD, bb & 15, bb >> 4, 0, tile);
  } else {
    router_body(x, wr, eidx, xb, (b - 2304) * 4);
  }
}

// counting sort -> perm + 128-row tile table (scratch-free, proven R1-R4)
__global__ __launch_bounds__(SORTT) void sort_kernel(
    const int* __restrict__ eidx, int* __restrict__ ntiles, int* __restrict__ tile_e,
    int* __restrict__ tile_base, int* __restrict__ tile_len, int* __restrict__ perm) {
  __shared__ int h[NE][SORTT];
  __shared__ int off_sh[NE];
  __shared__ int tot[NE];
  int t = threadIdx.x;
  int wave = t >> 6, lane = t & 63;
  const int base = t * TPT;

  int4 e0 = *(const int4*)(eidx + base);
  int4 e1 = *(const int4*)(eidx + base + 4);
  int4 e2 = *(const int4*)(eidx + base + 8);
  int4 e3 = *(const int4*)(eidx + base + 12);
  int ex[TPT] = {e0.x, e0.y, e0.z, e0.w, e1.x, e1.y, e1.z, e1.w,
                 e2.x, e2.y, e2.z, e2.w, e3.x, e3.y, e3.z, e3.w};
  int cnt0 = 0, cnt1 = 0, cnt2 = 0, cnt3 = 0, cnt4 = 0, cnt5 = 0, cnt6 = 0, cnt7 = 0;
#pragma unroll
  for (int i = 0; i < TPT; i++) {
    int e = ex[i];
    cnt0 += (e == 0); cnt1 += (e == 1); cnt2 += (e == 2); cnt3 += (e == 3);
    cnt4 += (e == 4); cnt5 += (e == 5); cnt6 += (e == 6); cnt7 += (e == 7);
  }
  h[0][t] = cnt0; h[1][t] = cnt1; h[2][t] = cnt2; h[3][t] = cnt3;
  h[4][t] = cnt4; h[5][t] = cnt5; h[6][t] = cnt6; h[7][t] = cnt7;
  __syncthreads();

  {
    int e = wave;
    int v[8], s = 0;
#pragma unroll
    for (int i = 0; i < 8; i++) { v[i] = h[e][lane * 8 + i]; s += v[i]; }
    int inc = s;
#pragma unroll
    for (int d = 1; d < 64; d <<= 1) {
      int o = __shfl_up(inc, d, 64);
      if (lane >= d) inc += o;
    }
    int exc = inc - s;
#pragma unroll
    for (int i = 0; i < 8; i++) { h[e][lane * 8 + i] = exc; exc += v[i]; }
    if (lane == 63) tot[e] = inc;
  }
  __syncthreads();

  if (t == 0) {
    int s = 0, tt = 0;
    for (int e = 0; e < NE; e++) {
      off_sh[e] = s;
      int c = tot[e];
      for (int b = 0; b < c; b += 128) {
        tile_e[tt] = e;
        tile_base[tt] = s + b;
        tile_len[tt] = (c - b < 128) ? (c - b) : 128;
        tt++;
      }
      s += c;
    }
    *ntiles = tt;
  }
  __syncthreads();

  int c0c = off_sh[0] + h[0][t], c1c = off_sh[1] + h[1][t];
  int c2c = off_sh[2] + h[2][t], c3c = off_sh[3] + h[3][t];
  int c4c = off_sh[4] + h[4][t], c5c = off_sh[5] + h[5][t];
  int c6c = off_sh[6] + h[6][t], c7c = off_sh[7] + h[7][t];
#pragma unroll
  for (int i = 0; i < TPT; i++) {
    int e = ex[i];
    int pos = c0c;
    pos = (e == 1) ? c1c : pos; pos = (e == 2) ? c2c : pos;
    pos = (e == 3) ? c3c : pos; pos = (e == 4) ? c4c : pos;
    pos = (e == 5) ? c5c : pos; pos = (e == 6) ? c6c : pos;
    pos = (e == 7) ? c7c : pos;
    perm[pos] = base + i;
    c0c += (e == 0); c1c += (e == 1); c2c += (e == 2); c3c += (e == 3);
    c4c += (e == 4); c5c += (e == 5); c6c += (e == 6); c7c += (e == 7);
  }
}

// ---------------- GEMM kernels (R4 internals + refined XCD remap) --------
// 128x128 tile, BK=64, 4 waves (2x2), acc[4][4], 16x16x32 bf16.  LDS
// [row][64] bf16, 16B chunks XOR-swizzled by (row&7): 0 bank conflicts.
// stage -> sync -> compute -> sync; ~3-4 independent 4-wave blocks/CU.
//
// R11 remap refinement: R9/R10's (t-quarter x n-HALF) pinned a 4.2 MB
// B-slice per XCD -- just over the 4 MB XCD L2, so B re-streams partially
// fell to L3 every tile-advance.  Now (t-half x n-QUARTER): resident B
// slice = 8 nb x 128 x 1024 x 2 B = 2.1 MB (fits), and each A-panel is
// shared by the 8 co-located n-blocks (L2-hit after first touch).

__global__ __launch_bounds__(256, 2) void ffn1_kernel(
    const unsigned short* __restrict__ xb, const unsigned short* __restrict__ w1t,
    const float* __restrict__ b1, const int* __restrict__ perm,
    const int* __restrict__ ntiles, const int* __restrict__ tile_e,
    const int* __restrict__ tile_base, const int* __restrict__ tile_len,
    unsigned short* __restrict__ interb) {
  // grid 2304 = 8 xcd x 288 slots.  xcd = (t-half(36) x n-quarter(8 nb)).
  // slot: nb_local = s & 7 (fast), tile-local = s >> 3 (slow).
  int w = blockIdx.x;
  int x = w & 7, s = w >> 3;         // xcd, slot 0..287
  int nq = x & 3, th = x >> 2;       // n-quarter, t-half
  int t = th * 36 + (s >> 3);        // tile 0..71
  if (t >= *ntiles) return;
  int nb = (nq * 8 + (s & 7)) * 128;
  int e = tile_e[t], base = tile_base[t], len = tile_len[t];

  __shared__ unsigned short lA[128 * 64];
  __shared__ unsigned short lB[128 * 64];

  int tid = threadIdx.x;
  int wave = tid >> 6, lane = tid & 63;
  int lr = lane >> 3;              // row-within-8-row-chunk
  int chunk = (lane & 7) ^ lr;     // swizzled 16B chunk selector

  const unsigned short* gA[4];
  const unsigned short* gB[4];
#pragma unroll
  for (int qq = 0; qq < 4; qq++) {
    int c = wave * 4 + qq;
    int tr = c * 8 + lr;
    int token = perm[base + (tr < len ? tr : len - 1)];  // clamp tail (stores masked)
    gA[qq] = xb + (size_t)token * HD + chunk * 8;
    int nr = nb + c * 8 + lr;
    gB[qq] = w1t + ((size_t)e * ID + nr) * HD + chunk * 8;
  }

  floatx4 acc[4][4];
#pragma unroll
  for (int i = 0; i < 4; i++)
#pragma unroll
    for (int j = 0; j < 4; j++) acc[i][j] = (floatx4){0.f, 0.f, 0.f, 0.f};

  int wm = (wave >> 1) * 64, wn = (wave & 1) * 64;
  int c15 = lane & 15, q4 = lane >> 4;

  for (int ko = 0; ko < HD / 64; ko++) {
#pragma unroll
    for (int qq = 0; qq < 4; qq++) {
      int c = wave * 4 + qq;
      async_ld16(gA[qq] + ko * 64, &lA[c * 512]);
      async_ld16(gB[qq] + ko * 64, &lB[c * 512]);
    }
    __syncthreads();
#pragma unroll
    for (int kk = 0; kk < 2; kk++) {
      short8 af[4], bfr[4];
#pragma unroll
      for (int i = 0; i < 4; i++) {
        int m = wm + i * 16 + c15;
        int sa = (kk * 4 + q4) ^ (m & 7);
        af[i] = *(const short8*)&lA[m * 64 + sa * 8];
        int n = wn + i * 16 + c15;
        int sb = (kk * 4 + q4) ^ (n & 7);
        bfr[i] = *(const short8*)&lB[n * 64 + sb * 8];
      }
#pragma unroll
      for (int i = 0; i < 4; i++)
#pragma unroll
        for (int j = 0; j < 4; j++)
          acc[i][j] = __builtin_amdgcn_mfma_f32_16x16x32_bf16(af[i], bfr[j], acc[i][j], 0, 0, 0);
    }
    __syncthreads();
  }

#pragma unroll
  for (int i = 0; i < 4; i++) {
#pragma unroll
    for (int r = 0; r < 4; r++) {
      int tr = wm + i * 16 + q4 * 4 + r;
      if (tr >= len) continue;
      int token = perm[base + tr];
#pragma unroll
      for (int j = 0; j < 4; j++) {
        int col = nb + wn + j * 16 + c15;
        float v = acc[i][j][r] + b1[e * ID + col];
        v = 0.5f * v * (1.0f + erff(v * 0.70710678118654752f));  // exact GELU
        interb[(size_t)token * ID + col] = f2bf(v);
      }
    }
  }
}

// full-K ffn2, fused bias + residual; writes pre-LN y (fp32) to d_out.
__global__ __launch_bounds__(256, 2) void ffn2_kernel(
    const unsigned short* __restrict__ interb, const unsigned short* __restrict__ wot,
    const float* __restrict__ bo, const float* __restrict__ x, float* __restrict__ y) {
  // grid 512 = 8 xcd x 64 slots.  xcd = (m-half(32 tm) x n-quarter(2 nb)):
  // resident wot slice = 2 x 128 x 4096 x 2 B = 2.1 MB (fits 4 MB L2);
  // each interb A-panel shared by the 2 co-located n-blocks.
  int w = blockIdx.x;
  int x8 = w & 7, s = w >> 3;        // xcd, slot 0..63
  int nq = x8 & 3, mh = x8 >> 2;     // n-quarter, m-half
  int tm = mh * 32 + (s >> 1);       // m-tile 0..63
  int nb = (nq * 2 + (s & 1)) * 128; // n-block 0..7

  __shared__ unsigned short lA[128 * 64];
  __shared__ unsigned short lB[128 * 64];

  int tid = threadIdx.x;
  int wave = tid >> 6, lane = tid & 63;
  int lr = lane >> 3;
  int chunk = (lane & 7) ^ lr;

  const unsigned short* gA[4];
  const unsigned short* gB[4];
#pragma unroll
  for (int qq = 0; qq < 4; qq++) {
    int c = wave * 4 + qq;
    int row = tm * 128 + c * 8 + lr;
    gA[qq] = interb + (size_t)row * ID + chunk * 8;
    int nr = nb + c * 8 + lr;
    gB[qq] = wot + (size_t)nr * ID + chunk * 8;
  }

  floatx4 acc[4][4];
#pragma unroll
  for (int i = 0; i < 4; i++)
#pragma unroll
    for (int j = 0; j < 4; j++) acc[i][j] = (floatx4){0.f, 0.f, 0.f, 0.f};

  int wm = (wave >> 1) * 64, wn = (wave & 1) * 64;
  int c15 = lane & 15, q4 = lane >> 4;

  for (int ko = 0; ko < ID / 64; ko++) {
#pragma unroll
    for (int qq = 0; qq < 4; qq++) {
      int c = wave * 4 + qq;
      async_ld16(gA[qq] + ko * 64, &lA[c * 512]);
      async_ld16(gB[qq] + ko * 64, &lB[c * 512]);
    }
    __syncthreads();
#pragma unroll
    for (int kk = 0; kk < 2; kk++) {
      short8 af[4], bfr[4];
#pragma unroll
      for (int i = 0; i < 4; i++) {
        int m = wm + i * 16 + c15;
        int sa = (kk * 4 + q4) ^ (m & 7);
        af[i] = *(const short8*)&lA[m * 64 + sa * 8];
        int n = wn + i * 16 + c15;
        int sb = (kk * 4 + q4) ^ (n & 7);
        bfr[i] = *(const short8*)&lB[n * 64 + sb * 8];
      }
#pragma unroll
      for (int i = 0; i < 4; i++)
#pragma unroll
        for (int j = 0; j < 4; j++)
          acc[i][j] = __builtin_amdgcn_mfma_f32_16x16x32_bf16(af[i], bfr[j], acc[i][j], 0, 0, 0);
    }
    __syncthreads();
  }

#pragma unroll
  for (int i = 0; i < 4; i++) {
#pragma unroll
    for (int r = 0; r < 4; r++) {
      int row = tm * 128 + wm + i * 16 + q4 * 4 + r;
#pragma unroll
      for (int j = 0; j < 4; j++) {
        int col = nb + wn + j * 16 + c15;
        float v = acc[i][j][r] + bo[col] + x[(size_t)row * HD + col];
        y[(size_t)row * HD + col] = v;  // pre-LN y staged in d_out
      }
    }
  }
}

__global__ void ln_kernel(float* __restrict__ y, const float* __restrict__ gamma,
                          const float* __restrict__ beta) {
  int row = blockIdx.x, t = threadIdx.x;
  int lane = t & 63, wave = t >> 6;
  float* yr = y + (size_t)row * HD;
  float4 v = *(const float4*)(yr + t * 4);
  float s = v.x + v.y + v.z + v.w;
  float ss = v.x * v.x + v.y * v.y + v.z * v.z + v.w * v.w;
#pragma unroll
  for (int m = 32; m >= 1; m >>= 1) {
    s += __shfl_xor(s, m, 64);
    ss += __shfl_xor(ss, m, 64);
  }
  __shared__ float sred[4], ssred[4];
  if (lane == 0) { sred[wave] = s; ssred[wave] = ss; }
  __syncthreads();
  s = sred[0] + sred[1] + sred[2] + sred[3];
  ss = ssred[0] + ssred[1] + ssred[2] + ssred[3];
  float mu = s * (1.0f / HD);
  float var = ss * (1.0f / HD) - mu * mu;
  float rs = rsqrtf(var + 1e-12f);
  float4 g = *(const float4*)(gamma + t * 4);
  float4 b = *(const float4*)(beta + t * 4);
  float4 o;
  o.x = (v.x - mu) * rs * g.x + b.x;
  o.y = (v.y - mu) * rs * g.y + b.y;
  o.z = (v.z - mu) * rs * g.z + b.z;
  o.w = (v.w - mu) * rs * g.w + b.w;
  *(float4*)(yr + t * 4) = o;
}

// ---------------- host launcher ----------------

extern "C" void kernel_launch(void* const* d_in, const int* in_sizes, int n_in,
                              void* d_out, int out_size, void* d_ws, size_t ws_size,
                              hipStream_t stream) {
  const float* x     = (const float*)d_in[0];
  const float* wr    = (const float*)d_in[1];
  const float* w1    = (const float*)d_in[2];
  const float* b1    = (const float*)d_in[3];
  const float* wo    = (const float*)d_in[4];
  const float* bo    = (const float*)d_in[5];
  const float* gamma = (const float*)d_in[6];
  const float* beta  = (const float*)d_in[7];
  float* out = (float*)d_out;

  char* p = (char*)d_ws;
  unsigned short* w1t = (unsigned short*)p; p += (size_t)NE * ID * HD * 2;   // 67 MB
  unsigned short* wot = (unsigned short*)p; p += (size_t)HD * ID * 2;        // 8.4 MB
  unsigned short* xb  = (unsigned short*)p; p += (size_t)NTOK * HD * 2;      // 16.8 MB
  unsigned short* interb = (unsigned short*)p; p += (size_t)NTOK * ID * 2;   // 67 MB
  int* eidx = (int*)p; p += (size_t)NTOK * 4;
  int* perm = (int*)p; p += (size_t)NTOK * 4;
  int* ints = (int*)p;
  int* ntiles    = ints;        // 1
  int* tile_e    = ints + 8;    // 72
  int* tile_base = ints + 80;   // 72
  int* tile_len  = ints + 152;  // 72

  preamble_kernel<<<4352, 256, 0, stream>>>(x, wr, w1, wo, w1t, wot, eidx, xb);
  sort_kernel<<<1, SORTT, 0, stream>>>(eidx, ntiles, tile_e, tile_base, tile_len, perm);
  ffn1_kernel<<<2304, 256, 0, stream>>>(
      xb, w1t, b1, perm, ntiles, tile_e, tile_base, tile_len, interb);
  ffn2_kernel<<<512, 256, 0, stream>>>(interb, wot, bo, x, out);
  ln_kernel<<<NTOK, 256, 0, stream>>>(out, gamma, beta);
}